// Round 2
// baseline (6002.029 us; speedup 1.0000x reference)
//
#include <hip/hip_runtime.h>
#include <hip/hip_fp16.h>

constexpr int Bn = 4, Tn = 2048, Dn = 1024, Hn = 8, Kn = 128, Vn = 128;
constexpr int Sn = 512, Cn = 256, Rn = 8, Wn = 512;
constexpr float NEGV = 1.0e30f;
constexpr float INV_TAU = 0.08838834764831845f;  // 1/sqrt(128)

// ---------------- RMSNorm ----------------
__global__ __launch_bounds__(256) void rmsnorm_k(const float* __restrict__ x,
                                                 const float* __restrict__ g,
                                                 float* __restrict__ xt) {
  const int row = blockIdx.x;
  const int tid = threadIdx.x;
  const float4* xr = reinterpret_cast<const float4*>(x + (size_t)row * Dn);
  float4 v = xr[tid];
  float ss = v.x * v.x + v.y * v.y + v.z * v.z + v.w * v.w;
#pragma unroll
  for (int o = 32; o > 0; o >>= 1) ss += __shfl_xor(ss, o);
  __shared__ float red[4];
  if ((tid & 63) == 0) red[tid >> 6] = ss;
  __syncthreads();
  const float tot = red[0] + red[1] + red[2] + red[3];
  const float sc = rsqrtf(tot * (1.0f / Dn) + 1e-6f);
  const float4 gv = reinterpret_cast<const float4*>(g)[tid];
  float4 ov;
  ov.x = v.x * sc * gv.x;
  ov.y = v.y * sc * gv.y;
  ov.z = v.z * sc * gv.z;
  ov.w = v.w * sc * gv.w;
  reinterpret_cast<float4*>(xt + (size_t)row * Dn)[tid] = ov;
}

// ---------------- Generic f32 tiled GEMM (128x128x16, 256 thr, 8x8 micro) ---
// MODE 1: NN, f32 out row-major, B row stride = ldb (QKV head slice, out-proj)
// MODE 2: NT (B given as [N,KD]), A += abias[kd], f16 out row-major (G1/G2)
// MODE 3: NT, f32 out row-major (k.cb^T dots for argmin)
template <int MODE>
__global__ __launch_bounds__(256) void gemm_k(const float* __restrict__ A,
                                              const float* __restrict__ Bw,
                                              void* __restrict__ Cout,
                                              const float* __restrict__ abias,
                                              int M, int N, int KD, int ldb) {
  __shared__ float As[16][132];
  __shared__ float Bs[16][132];
  const int tid = threadIdx.x;
  const int m0 = blockIdx.x * 128;
  const int n0 = blockIdx.y * 128;
  const float* Ab = A;
  const float* Bb = Bw;
  const int lr = tid >> 2;          // 0..63
  const int lc4 = (tid & 3) * 4;    // 0,4,8,12
  const int bkr = tid >> 5;         // 0..7
  const int bj4 = (tid & 31) * 4;   // 0..124

  auto ldA = [&](int kt, int half) {
    const int row = lr + half * 64;
    float4 v = *reinterpret_cast<const float4*>(
        &Ab[(size_t)(m0 + row) * KD + kt + lc4]);
    if (MODE == 2) {
      const float* bp = &abias[kt + lc4];
      v.x += bp[0];
      v.y += bp[1];
      v.z += bp[2];
      v.w += bp[3];
    }
    return v;
  };
  auto ldB = [&](int kt, int half) {
    if (MODE >= 2) {
      const int row = lr + half * 64;
      return *reinterpret_cast<const float4*>(
          &Bb[(size_t)(n0 + row) * KD + kt + lc4]);
    } else {
      const int kr = bkr + half * 8;
      return *reinterpret_cast<const float4*>(
          &Bb[(size_t)(kt + kr) * ldb + n0 + bj4]);
    }
  };

  float4 pa0 = ldA(0, 0), pa1 = ldA(0, 1);
  float4 pb0 = ldB(0, 0), pb1 = ldB(0, 1);

  float acc[8][8] = {};
  const int mr = (tid >> 4) * 8;
  const int nr = (tid & 15) * 8;

  for (int kt = 0; kt < KD; kt += 16) {
    __syncthreads();
    As[lc4 + 0][lr] = pa0.x;
    As[lc4 + 1][lr] = pa0.y;
    As[lc4 + 2][lr] = pa0.z;
    As[lc4 + 3][lr] = pa0.w;
    As[lc4 + 0][lr + 64] = pa1.x;
    As[lc4 + 1][lr + 64] = pa1.y;
    As[lc4 + 2][lr + 64] = pa1.z;
    As[lc4 + 3][lr + 64] = pa1.w;
    if (MODE >= 2) {
      Bs[lc4 + 0][lr] = pb0.x;
      Bs[lc4 + 1][lr] = pb0.y;
      Bs[lc4 + 2][lr] = pb0.z;
      Bs[lc4 + 3][lr] = pb0.w;
      Bs[lc4 + 0][lr + 64] = pb1.x;
      Bs[lc4 + 1][lr + 64] = pb1.y;
      Bs[lc4 + 2][lr + 64] = pb1.z;
      Bs[lc4 + 3][lr + 64] = pb1.w;
    } else {
      *reinterpret_cast<float4*>(&Bs[bkr][bj4]) = pb0;
      *reinterpret_cast<float4*>(&Bs[bkr + 8][bj4]) = pb1;
    }
    __syncthreads();
    if (kt + 16 < KD) {
      pa0 = ldA(kt + 16, 0);
      pa1 = ldA(kt + 16, 1);
      pb0 = ldB(kt + 16, 0);
      pb1 = ldB(kt + 16, 1);
    }
#pragma unroll
    for (int c = 0; c < 16; ++c) {
      float a[8], bv[8];
#pragma unroll
      for (int i = 0; i < 8; ++i) {
        a[i] = As[c][mr + i];
        bv[i] = Bs[c][nr + i];
      }
#pragma unroll
      for (int i = 0; i < 8; ++i)
#pragma unroll
        for (int j = 0; j < 8; ++j) acc[i][j] = fmaf(a[i], bv[j], acc[i][j]);
    }
  }

  if (MODE == 2) {
    __half* O = reinterpret_cast<__half*>(Cout);
#pragma unroll
    for (int i = 0; i < 8; ++i)
#pragma unroll
      for (int j = 0; j < 8; ++j)
        O[(size_t)(m0 + mr + i) * N + n0 + nr + j] = __float2half(acc[i][j]);
  } else {
    float* O = reinterpret_cast<float*>(Cout);
#pragma unroll
    for (int i = 0; i < 8; ++i) {
      const size_t ro = (size_t)(m0 + mr + i) * N + n0 + nr;
      *reinterpret_cast<float4*>(&O[ro]) =
          make_float4(acc[i][0], acc[i][1], acc[i][2], acc[i][3]);
      *reinterpret_cast<float4*>(&O[ro + 4]) =
          make_float4(acc[i][4], acc[i][5], acc[i][6], acc[i][7]);
    }
  }
}

// ---------------- codebook squared norms (all heads) ----------------
__global__ __launch_bounds__(256) void cb2_k(const float* __restrict__ cb,
                                             float* __restrict__ cb2v) {
  const int idx = blockIdx.x * 256 + threadIdx.x;  // < H*S
  const float4* rp = reinterpret_cast<const float4*>(cb + (size_t)idx * Kn);
  float ss = 0.f;
#pragma unroll 8
  for (int i = 0; i < Kn / 4; ++i) {
    const float4 v = rp[i];
    ss += v.x * v.x + v.y * v.y + v.z * v.z + v.w * v.w;
  }
  cb2v[idx] = ss;
}

// ---------------- argmin + scatter (per head) ----------------
__global__ __launch_bounds__(256) void argmin_k(const float* __restrict__ dot,
                                                const float* __restrict__ cb2v,
                                                const float* __restrict__ vb,
                                                int* __restrict__ zb,
                                                float* __restrict__ d1b,
                                                float* __restrict__ dvb) {
  const int m = blockIdx.x * 4 + (threadIdx.x >> 6);  // 0..B*T-1
  const int lane = threadIdx.x & 63;
  const int b = m >> 11;      // T = 2048
  const int t = m & (Tn - 1);
  const int r = t >> 8;       // C = 256
  const float* row = dot + (size_t)m * Sn;
  float best = 3.0e38f;
  int bi = 0;
#pragma unroll
  for (int i = 0; i < Sn / 64; ++i) {
    const int s = lane + i * 64;
    const float d2 = cb2v[s] - 2.0f * row[s];
    if (d2 < best) {
      best = d2;
      bi = s;
    }
  }
#pragma unroll
  for (int o = 32; o > 0; o >>= 1) {
    const float ob = __shfl_xor(best, o);
    const int oi = __shfl_xor(bi, o);
    if (ob < best || (ob == best && oi < bi)) {
      best = ob;
      bi = oi;
    }
  }
  if (lane == 0) {
    zb[m] = bi;
    atomicAdd(&d1b[((size_t)b * Rn + r) * Sn + bi], 1.0f);  // exact (ints)
  }
  const float* vrow = vb + (size_t)m * Vn;
  float* drow = dvb + (((size_t)b * Rn + r) * Sn + bi) * Vn;
  atomicAdd(&drow[lane], vrow[lane]);
  atomicAdd(&drow[lane + 64], vrow[lane + 64]);
}

// ---------------- cumulative counts + cache bias (per head) ----------------
__global__ __launch_bounds__(256) void stats_k(const float* __restrict__ d1,
                                               float* __restrict__ d1c,
                                               float* __restrict__ biasv) {
  const int idx = blockIdx.x * 256 + threadIdx.x;  // (b, s) < B*S
  const int s = idx & (Sn - 1);
  const int b = idx >> 9;
  float cnt = 0.f, h1 = 0.f, h2 = 0.f;
#pragma unroll
  for (int r = 0; r < Rn; ++r) {
    const size_t o = ((size_t)b * Rn + r) * Sn + s;
    cnt += d1[o];
    d1c[o] = cnt;
    const float lower = (r >= 2) ? h2 : 0.f;
    biasv[o] = (lower > 0.f) ? logf(fmaxf(lower, 1.f)) : -NEGV;
    h2 = h1;
    h1 = cnt;
  }
}

// ---------------- upper_div_lower = cumsum(dv)[r-2] / max(d1c[r-2],1) -------
__global__ __launch_bounds__(256) void udl_k(float* __restrict__ dv,
                                             const float* __restrict__ d1c) {
  const int flat = blockIdx.x * 256 + threadIdx.x;  // < S*V/4
  const int s = flat >> 5;
  const int v4 = (flat & 31) * 4;
  const int b = blockIdx.y;
  float4 p1 = make_float4(0, 0, 0, 0), p2 = make_float4(0, 0, 0, 0);
#pragma unroll
  for (int r = 0; r < Rn; ++r) {
    const size_t base = (((size_t)b * Rn + r) * Sn + s) * Vn + v4;
    const float4 cur = *reinterpret_cast<const float4*>(&dv[base]);
    float4 ov = make_float4(0, 0, 0, 0);
    if (r >= 2) {
      const float dcv = d1c[((size_t)b * Rn + (r - 2)) * Sn + s];
      const float inv = 1.0f / fmaxf(dcv, 1.0f);
      ov = make_float4(p2.x * inv, p2.y * inv, p2.z * inv, p2.w * inv);
    }
    *reinterpret_cast<float4*>(&dv[base]) = ov;  // in-place: read before write
    const float4 np1 = make_float4(p1.x + cur.x, p1.y + cur.y, p1.z + cur.z,
                                   p1.w + cur.w);
    p2 = p1;
    p1 = np1;
  }
}

// ---------------- fused attention (per head; gathered logits, online SM) ----
__global__ __launch_bounds__(256) void attn_k(
    const __half* __restrict__ g1, const __half* __restrict__ g2,
    const float* __restrict__ biasv, const int* __restrict__ zb,
    const float* __restrict__ udl, const float* __restrict__ vb,
    float* __restrict__ outp) {
  __shared__ float Ps[64][65];
  __shared__ float Vs[64][132];
  __shared__ int zsm[64];
  const int tid = threadIdx.x;
  const int qt = blockIdx.x;       // 0..3
  const int b = blockIdx.y >> 3;   // grid.y = B*R
  const int r = blockIdx.y & 7;
  const int ql = tid >> 2;
  const int part = tid & 3;
  const int c = qt * 64 + ql;      // position in block [0,256)
  const int tq = r * Cn + c;
  const size_t g1row = ((size_t)b * Tn + tq) * Sn;
  const size_t g2row = ((size_t)b * Tn + tq) * Wn;
  const size_t brow = ((size_t)b * Rn + r) * Sn;

  float m = -NEGV, l = 0.f;
  float Oa[32];
#pragma unroll
  for (int i = 0; i < 32; ++i) Oa[i] = 0.f;

  for (int ch = 0; ch < 16; ++ch) {
    const bool cacheCh = (ch < 8);
    if (!cacheCh && tid < 64) {
      const int w = (ch - 8) * 64 + tid;
      const int tk = (r - 1) * Cn + w;
      zsm[tid] = (tk >= 0) ? zb[(size_t)b * Tn + tk] : 0;
    }
    __syncthreads();

    float lg[16];
    if (cacheCh) {
      const int s0 = ch * 64 + part * 16;
#pragma unroll
      for (int jj = 0; jj < 16; ++jj) {
        const int s = s0 + jj;
        lg[jj] = __half2float(g1[g1row + s]) * INV_TAU + biasv[brow + s];
      }
    } else {
      const int j0 = part * 16;
      const int w0 = (ch - 8) * 64;
#pragma unroll
      for (int jj = 0; jj < 16; ++jj) {
        const int w = w0 + j0 + jj;
        float v = -NEGV;
        if (w <= c + Cn && !(r == 0 && w < Cn)) {
          const int zc = zsm[j0 + jj];
          v = (__half2float(g1[g1row + zc]) +
               __half2float(g2[g2row + (w + Cn - 1 - c)])) *
              INV_TAU;
        }
        lg[jj] = v;
      }
    }
    float cmax = lg[0];
#pragma unroll
    for (int jj = 1; jj < 16; ++jj) cmax = fmaxf(cmax, lg[jj]);
    cmax = fmaxf(cmax, __shfl_xor(cmax, 1));
    cmax = fmaxf(cmax, __shfl_xor(cmax, 2));
    const float mnew = fmaxf(m, cmax);
    const float sc = __expf(m - mnew);
    float csum = 0.f;
#pragma unroll
    for (int jj = 0; jj < 16; ++jj) {
      const float p = __expf(lg[jj] - mnew);
      csum += p;
      Ps[ql][part * 16 + jj] = p;
    }
    csum += __shfl_xor(csum, 1);
    csum += __shfl_xor(csum, 2);
    l = l * sc + csum;
#pragma unroll
    for (int i = 0; i < 32; ++i) Oa[i] *= sc;
    m = mnew;

    // stage V rows (cache -> udl rows, recent -> raw v rows)
    if (cacheCh) {
      const float* src = udl + (((size_t)b * Rn + r) * Sn + ch * 64) * Vn;
      for (int u = tid; u < 2048; u += 256) {
        const int row = u >> 5;
        const int c4 = (u & 31) * 4;
        *reinterpret_cast<float4*>(&Vs[row][c4]) =
            *reinterpret_cast<const float4*>(&src[(size_t)row * Vn + c4]);
      }
    } else {
      const int tk0 = (r - 1) * Cn + (ch - 8) * 64;
      const float* src = vb + (size_t)b * Tn * Vn;
      for (int u = tid; u < 2048; u += 256) {
        const int row = u >> 5;
        const int c4 = (u & 31) * 4;
        int srow = tk0 + row;
        if (srow < 0) srow = 0;  // masked rows (P=0) read token 0 harmlessly
        *reinterpret_cast<float4*>(&Vs[row][c4]) =
            *reinterpret_cast<const float4*>(&src[(size_t)srow * Vn + c4]);
      }
    }
    __syncthreads();
    // PV accumulate
#pragma unroll 4
    for (int j = 0; j < 64; ++j) {
      const float pj = Ps[ql][j];
      const float* vr = &Vs[j][part * 32];
#pragma unroll
      for (int i = 0; i < 32; ++i) Oa[i] = fmaf(pj, vr[i], Oa[i]);
    }
    __syncthreads();
  }
  const float invl = 1.0f / l;
  float* orow = outp + ((size_t)b * Tn + tq) * (Hn * Vn) + part * 32;
#pragma unroll
  for (int i4 = 0; i4 < 8; ++i4) {
    *reinterpret_cast<float4*>(&orow[i4 * 4]) =
        make_float4(Oa[i4 * 4] * invl, Oa[i4 * 4 + 1] * invl,
                    Oa[i4 * 4 + 2] * invl, Oa[i4 * 4 + 3] * invl);
  }
}

// ---------------- launcher (per-head passes; ws ~100 MiB) ----------------
extern "C" void kernel_launch(void* const* d_in, const int* in_sizes, int n_in,
                              void* d_out, int out_size, void* d_ws,
                              size_t ws_size, hipStream_t stream) {
  (void)in_sizes;
  (void)n_in;
  (void)out_size;
  const float* x = (const float*)d_in[0];
  const float* g_ln = (const float*)d_in[1];
  const float* Wq = (const float*)d_in[2];
  const float* Wk = (const float*)d_in[3];
  const float* Wv = (const float*)d_in[4];
  const float* cb = (const float*)d_in[5];
  const float* xl_r = (const float*)d_in[6];
  const float* xl_u = (const float*)d_in[7];
  const float* xl_v = (const float*)d_in[8];
  const float* Wo = (const float*)d_in[9];
  float* out = (float*)d_out;

  float* W = (float*)d_ws;
  size_t o = 0;
  float* xt = W + o;    o += (size_t)Bn * Tn * Dn;        // 8,388,608
  float* aout = W + o;  o += (size_t)Bn * Tn * Hn * Vn;   // 8,388,608
  float* qh = W + o;    o += (size_t)Bn * Tn * Kn;        // 1,048,576
  float* kh = W + o;    o += (size_t)Bn * Tn * Kn;
  float* vh = W + o;    o += (size_t)Bn * Tn * Vn;
  float* dvh = W + o;   o += (size_t)Bn * Rn * Sn * Vn;   // 2,097,152
  float* d1h = W + o;   o += (size_t)Bn * Rn * Sn;        // 16,384
  float* d1ch = W + o;  o += (size_t)Bn * Rn * Sn;
  float* bbh = W + o;   o += (size_t)Bn * Rn * Sn;
  float* cb2b = W + o;  o += (size_t)Hn * Sn;             // 4,096
  int* zh = (int*)(W + o);  o += (size_t)Bn * Tn;         // 8,192
  float* dotb = W + o;  // f32 dot scratch aliases g1+g2 (exactly fits)
  __half* g1b = (__half*)dotb;
  __half* g2b = (__half*)(W + o + (size_t)Bn * Tn * Sn / 2);
  o += (size_t)Bn * Tn * Sn;                              // 4,194,304

  if (ws_size < o * sizeof(float)) return;  // ws too small: bail visibly

  rmsnorm_k<<<Bn * Tn, 256, 0, stream>>>(x, g_ln, xt);
  cb2_k<<<Hn * Sn / 256, 256, 0, stream>>>(cb, cb2b);

  for (int h = 0; h < Hn; ++h) {
    // zero dv + d1 (contiguous) — atomically accumulated this pass
    hipMemsetAsync(dvh, 0,
                   ((size_t)Bn * Rn * Sn * Vn + (size_t)Bn * Rn * Sn) *
                       sizeof(float),
                   stream);
    // per-head QKV projections: [8192,1024] x [1024,128]
    gemm_k<1><<<dim3(64, 1), 256, 0, stream>>>(xt, Wq + h * Kn, qh, nullptr,
                                               8192, 128, 1024, 1024);
    gemm_k<1><<<dim3(64, 1), 256, 0, stream>>>(xt, Wk + h * Kn, kh, nullptr,
                                               8192, 128, 1024, 1024);
    gemm_k<1><<<dim3(64, 1), 256, 0, stream>>>(xt, Wv + h * Vn, vh, nullptr,
                                               8192, 128, 1024, 1024);
    // k . codebook^T (f32, for argmin)
    gemm_k<3><<<dim3(64, 4), 256, 0, stream>>>(kh, cb + (size_t)h * Sn * Kn,
                                               dotb, nullptr, 8192, 512, 128,
                                               0);
    argmin_k<<<Bn * Tn / 4, 256, 0, stream>>>(dotb, cb2b + h * Sn, vh, zh, d1h,
                                              dvh);
    stats_k<<<Bn * Sn / 256, 256, 0, stream>>>(d1h, d1ch, bbh);
    udl_k<<<dim3(Sn * Vn / 4 / 256, Bn), 256, 0, stream>>>(dvh, d1ch);
    // G1 = (q+u).cb^T ; G2 = (q+v).xl_r^T  (f16, overwrite dot scratch)
    gemm_k<2><<<dim3(64, 4), 256, 0, stream>>>(qh, cb + (size_t)h * Sn * Kn,
                                               g1b, xl_u + h * Kn, 8192, 512,
                                               128, 0);
    gemm_k<2><<<dim3(64, 4), 256, 0, stream>>>(qh, xl_r + (size_t)h * Wn * Kn,
                                               g2b, xl_v + h * Kn, 8192, 512,
                                               128, 0);
    attn_k<<<dim3(4, Bn * Rn, 1), 256, 0, stream>>>(g1b, g2b, bbh, zh, dvh, vh,
                                                    aout + h * Vn);
  }

  // out = attn_out[B,T,H*V] x Wo[H*V, D]
  gemm_k<1><<<dim3(64, 8), 256, 0, stream>>>(aout, Wo, out, nullptr, 8192,
                                             1024, 1024, 1024);
}

// Round 3
// 2027.281 us; speedup vs baseline: 2.9606x; 2.9606x over previous
//
#include <hip/hip_runtime.h>
#include <hip/hip_fp16.h>

constexpr int Bn = 4, Tn = 2048, Dn = 1024, Hn = 8, Kn = 128, Vn = 128;
constexpr int Sn = 512, Cn = 256, Rn = 8, Wn = 512;
constexpr float NEGV = 1.0e30f;
constexpr float INV_TAU = 0.08838834764831845f;  // 1/sqrt(128)

// ---------------- RMSNorm ----------------
__global__ __launch_bounds__(256) void rmsnorm_k(const float* __restrict__ x,
                                                 const float* __restrict__ g,
                                                 float* __restrict__ xt) {
  const int row = blockIdx.x;
  const int tid = threadIdx.x;
  const float4* xr = reinterpret_cast<const float4*>(x + (size_t)row * Dn);
  float4 v = xr[tid];
  float ss = v.x * v.x + v.y * v.y + v.z * v.z + v.w * v.w;
#pragma unroll
  for (int o = 32; o > 0; o >>= 1) ss += __shfl_xor(ss, o);
  __shared__ float red[4];
  if ((tid & 63) == 0) red[tid >> 6] = ss;
  __syncthreads();
  const float tot = red[0] + red[1] + red[2] + red[3];
  const float sc = rsqrtf(tot * (1.0f / Dn) + 1e-6f);
  const float4 gv = reinterpret_cast<const float4*>(g)[tid];
  float4 ov;
  ov.x = v.x * sc * gv.x;
  ov.y = v.y * sc * gv.y;
  ov.z = v.z * sc * gv.z;
  ov.w = v.w * sc * gv.w;
  reinterpret_cast<float4*>(xt + (size_t)row * Dn)[tid] = ov;
}

// ------------- f32 NN GEMM 128x128x16, 8x8 micro -------------
// MODE 0: f32 out remapped [h=n0>>7][m][128]   (K projection)
// MODE 1: f32 out row-major [M][N]             (out projection)
// MODE 4: f16 out remapped [h=n0>>7][m][128]   (Q/V projections)
template <int MODE>
__global__ __launch_bounds__(256, 2) void gemm_k(const float* __restrict__ A,
                                                 const float* __restrict__ Bw,
                                                 void* __restrict__ Cout,
                                                 int M, int N, int KD,
                                                 int ldb) {
  __shared__ float As[16][132];
  __shared__ float Bs[16][132];
  const int tid = threadIdx.x;
  const int m0 = blockIdx.x * 128;
  const int n0 = blockIdx.y * 128;
  const int lr = tid >> 2, lc4 = (tid & 3) * 4;
  const int bkr = tid >> 5, bj4 = (tid & 31) * 4;

  auto ldA = [&](int kt, int half) {
    return *reinterpret_cast<const float4*>(
        &A[(size_t)(m0 + lr + half * 64) * KD + kt + lc4]);
  };
  auto ldB = [&](int kt, int half) {
    return *reinterpret_cast<const float4*>(
        &Bw[(size_t)(kt + bkr + half * 8) * ldb + n0 + bj4]);
  };

  float4 pa0 = ldA(0, 0), pa1 = ldA(0, 1);
  float4 pb0 = ldB(0, 0), pb1 = ldB(0, 1);

  float acc[8][8] = {};
  const int mr = (tid >> 4) * 8;
  const int nr = (tid & 15) * 8;

  for (int kt = 0; kt < KD; kt += 16) {
    __syncthreads();
    As[lc4 + 0][lr] = pa0.x;
    As[lc4 + 1][lr] = pa0.y;
    As[lc4 + 2][lr] = pa0.z;
    As[lc4 + 3][lr] = pa0.w;
    As[lc4 + 0][lr + 64] = pa1.x;
    As[lc4 + 1][lr + 64] = pa1.y;
    As[lc4 + 2][lr + 64] = pa1.z;
    As[lc4 + 3][lr + 64] = pa1.w;
    *reinterpret_cast<float4*>(&Bs[bkr][bj4]) = pb0;
    *reinterpret_cast<float4*>(&Bs[bkr + 8][bj4]) = pb1;
    __syncthreads();
    if (kt + 16 < KD) {
      pa0 = ldA(kt + 16, 0);
      pa1 = ldA(kt + 16, 1);
      pb0 = ldB(kt + 16, 0);
      pb1 = ldB(kt + 16, 1);
    }
#pragma unroll
    for (int c = 0; c < 16; ++c) {
      float a[8], bv[8];
#pragma unroll
      for (int i = 0; i < 8; ++i) {
        a[i] = As[c][mr + i];
        bv[i] = Bs[c][nr + i];
      }
#pragma unroll
      for (int i = 0; i < 8; ++i)
#pragma unroll
        for (int j = 0; j < 8; ++j) acc[i][j] = fmaf(a[i], bv[j], acc[i][j]);
    }
  }

  if (MODE == 1) {
    float* O = reinterpret_cast<float*>(Cout);
#pragma unroll
    for (int i = 0; i < 8; ++i) {
      const size_t ro = (size_t)(m0 + mr + i) * N + n0 + nr;
      *reinterpret_cast<float4*>(&O[ro]) =
          make_float4(acc[i][0], acc[i][1], acc[i][2], acc[i][3]);
      *reinterpret_cast<float4*>(&O[ro + 4]) =
          make_float4(acc[i][4], acc[i][5], acc[i][6], acc[i][7]);
    }
  } else if (MODE == 0) {
    float* O = reinterpret_cast<float*>(Cout) + (size_t)(n0 >> 7) * M * 128;
#pragma unroll
    for (int i = 0; i < 8; ++i) {
      const size_t ro = (size_t)(m0 + mr + i) * 128 + nr;
      *reinterpret_cast<float4*>(&O[ro]) =
          make_float4(acc[i][0], acc[i][1], acc[i][2], acc[i][3]);
      *reinterpret_cast<float4*>(&O[ro + 4]) =
          make_float4(acc[i][4], acc[i][5], acc[i][6], acc[i][7]);
    }
  } else {
    __half* O = reinterpret_cast<__half*>(Cout) + (size_t)(n0 >> 7) * M * 128;
#pragma unroll
    for (int i = 0; i < 8; ++i) {
      const size_t ro = (size_t)(m0 + mr + i) * 128 + nr;
#pragma unroll
      for (int k2 = 0; k2 < 4; ++k2)
        *reinterpret_cast<__half2*>(&O[ro + 2 * k2]) =
            __floats2half2_rn(acc[i][2 * k2], acc[i][2 * k2 + 1]);
    }
  }
}

// ---------------- codebook squared norms ----------------
__global__ __launch_bounds__(256) void cb2_k(const float* __restrict__ cb,
                                             float* __restrict__ cb2v) {
  const int idx = blockIdx.x * 256 + threadIdx.x;  // < H*S
  const float4* rp = reinterpret_cast<const float4*>(cb + (size_t)idx * Kn);
  float ss = 0.f;
#pragma unroll 8
  for (int i = 0; i < Kn / 4; ++i) {
    const float4 v = rp[i];
    ss += v.x * v.x + v.y * v.y + v.z * v.z + v.w * v.w;
  }
  cb2v[idx] = ss;
}

// ---------------- f32 -> f16 conversion (cb and xl_r) ----------------
__global__ __launch_bounds__(256) void cvt_k(const float* __restrict__ cb,
                                             const float* __restrict__ xlr,
                                             __half* __restrict__ cbh,
                                             __half* __restrict__ xlrh) {
  const int i = blockIdx.x * 256 + threadIdx.x;
  constexpr int NE = Hn * Sn * Kn;  // 524288
  if (i < NE)
    cbh[i] = __float2half(cb[i]);
  else
    xlrh[i - NE] = __float2half(xlr[i - NE]);
}

// ---------------- duv[h][j] = (xl_v - xl_u) . xl_r[h][j] ----------------
__global__ __launch_bounds__(256) void duv_k(const float* __restrict__ xlr,
                                             const float* __restrict__ xlu,
                                             const float* __restrict__ xlv,
                                             float* __restrict__ duv) {
  const int h = blockIdx.x;
  const float* up = xlu + h * Kn;
  const float* vp = xlv + h * Kn;
  for (int j = threadIdx.x; j < Wn; j += 256) {
    const float* rp = xlr + ((size_t)h * Wn + j) * Kn;
    float s = 0.f;
#pragma unroll 8
    for (int d = 0; d < Kn; ++d) s = fmaf(vp[d] - up[d], rp[d], s);
    duv[h * Wn + j] = s;
  }
}

// ---------------- fused dot + argmin (all heads) ----------------
__global__ __launch_bounds__(256, 2) void argmin2_k(
    const float* __restrict__ kb, const float* __restrict__ cb,
    const float* __restrict__ cb2v, int* __restrict__ zb) {
  __shared__ float As[16][132];
  __shared__ float Bs[16][132];
  const int tid = threadIdx.x;
  const int m0 = blockIdx.x * 128;
  const int h = blockIdx.y;
  const float* Ab = kb + (size_t)h * (Bn * Tn) * Kn;
  const float* Bb = cb + (size_t)h * Sn * Kn;
  const int lr = tid >> 2, lc4 = (tid & 3) * 4;
  const int mr = (tid >> 4) * 8, nr = (tid & 15) * 8;
  float best[8];
  int bidx[8];
#pragma unroll
  for (int i = 0; i < 8; ++i) {
    best[i] = 3.0e38f;
    bidx[i] = 0;
  }
  for (int s0 = 0; s0 < Sn; s0 += 128) {
    float acc[8][8] = {};
    for (int kt = 0; kt < Kn; kt += 16) {
      __syncthreads();
      {
        const float4 a0 = *reinterpret_cast<const float4*>(
            &Ab[(size_t)(m0 + lr) * Kn + kt + lc4]);
        const float4 a1 = *reinterpret_cast<const float4*>(
            &Ab[(size_t)(m0 + lr + 64) * Kn + kt + lc4]);
        const float4 b0 = *reinterpret_cast<const float4*>(
            &Bb[(size_t)(s0 + lr) * Kn + kt + lc4]);
        const float4 b1 = *reinterpret_cast<const float4*>(
            &Bb[(size_t)(s0 + lr + 64) * Kn + kt + lc4]);
        As[lc4 + 0][lr] = a0.x;
        As[lc4 + 1][lr] = a0.y;
        As[lc4 + 2][lr] = a0.z;
        As[lc4 + 3][lr] = a0.w;
        As[lc4 + 0][lr + 64] = a1.x;
        As[lc4 + 1][lr + 64] = a1.y;
        As[lc4 + 2][lr + 64] = a1.z;
        As[lc4 + 3][lr + 64] = a1.w;
        Bs[lc4 + 0][lr] = b0.x;
        Bs[lc4 + 1][lr] = b0.y;
        Bs[lc4 + 2][lr] = b0.z;
        Bs[lc4 + 3][lr] = b0.w;
        Bs[lc4 + 0][lr + 64] = b1.x;
        Bs[lc4 + 1][lr + 64] = b1.y;
        Bs[lc4 + 2][lr + 64] = b1.z;
        Bs[lc4 + 3][lr + 64] = b1.w;
      }
      __syncthreads();
#pragma unroll
      for (int c = 0; c < 16; ++c) {
        float a[8], bv[8];
#pragma unroll
        for (int i = 0; i < 8; ++i) {
          a[i] = As[c][mr + i];
          bv[i] = Bs[c][nr + i];
        }
#pragma unroll
        for (int i = 0; i < 8; ++i)
#pragma unroll
          for (int j = 0; j < 8; ++j) acc[i][j] = fmaf(a[i], bv[j], acc[i][j]);
      }
    }
#pragma unroll
    for (int i = 0; i < 8; ++i)
#pragma unroll
      for (int j = 0; j < 8; ++j) {
        const float d2 = cb2v[h * Sn + s0 + nr + j] - 2.0f * acc[i][j];
        if (d2 < best[i]) {
          best[i] = d2;
          bidx[i] = s0 + nr + j;
        }
      }
  }
#pragma unroll
  for (int xb = 1; xb <= 8; xb <<= 1) {
#pragma unroll
    for (int i = 0; i < 8; ++i) {
      const float ob = __shfl_xor(best[i], xb);
      const int oi = __shfl_xor(bidx[i], xb);
      if (ob < best[i] || (ob == best[i] && oi < bidx[i])) {
        best[i] = ob;
        bidx[i] = oi;
      }
    }
  }
  if ((tid & 15) == 0) {
#pragma unroll
    for (int i = 0; i < 8; ++i)
      zb[(size_t)h * (Bn * Tn) + m0 + mr + i] = bidx[i];
  }
}

// ------- scan: cumulative cluster stats -> udl (f16) + bias, no atomics ----
__global__ __launch_bounds__(256) void scan_k(const int* __restrict__ zb,
                                              const __half* __restrict__ vb,
                                              __half* __restrict__ udl,
                                              float* __restrict__ biasv) {
  __shared__ float acc[128][128];
  __shared__ float cnt[128];
  const int tid = threadIdx.x;
  const int sc = blockIdx.x, b = blockIdx.y, h = blockIdx.z;
  const int s0 = sc * 128;
  for (int i = tid; i < 128 * 128; i += 256) acc[i >> 7][i & 127] = 0.f;
  if (tid < 128) cnt[tid] = 0.f;
  __syncthreads();
  const size_t tokH = (size_t)h * (Bn * Tn) + (size_t)b * Tn;
  const int dd = tid & 127, halfh = tid >> 7;
  for (int r = 0; r < Rn; ++r) {
    // write udl[r] (= cum through r-2) and bias[r]
    for (int i = tid; i < 128 * 128; i += 256) {
      const int srow = i >> 7, d = i & 127;
      const float c = cnt[srow];
      const float v = acc[srow][d] / fmaxf(c, 1.f);
      udl[((((size_t)h * Bn + b) * Rn + r) * Sn + s0 + srow) * Vn + d] =
          __float2half(v);
    }
    if (tid < 128) {
      const float c = cnt[tid];
      biasv[(((size_t)h * Bn + b) * Rn + r) * Sn + s0 + tid] =
          (c > 0.f) ? logf(c) : -NEGV;
    }
    __syncthreads();
    // add tokens of block r-1 (so next iteration's state = cum through r-1)
    if (r >= 1 && r < 7) {
      const int tb = (r - 1) * Cn;
#pragma unroll 4
      for (int u = 0; u < 128; ++u) {
        const int tok = tb + u * 2 + halfh;
        const int s = zb[tokH + tok];
        if (s >= s0 && s < s0 + 128) {
          const float v = __half2float(vb[(tokH + tok) * Vn + dd]);
          atomicAdd(&acc[s - s0][dd], v);
          if (dd == 0) atomicAdd(&cnt[s - s0], 1.0f);
        }
      }
    }
    __syncthreads();
  }
}

// ---------------- fused attention (all heads, fused logits) ----------------
// block: (qt, b*8+r, h); 256 thr; rowg=tid>>4 owns rows rowg*4+i (c-local),
// colg=tid&15 owns chunk-cols colg+16*j ; PV dims colg*8..+8
__global__ __launch_bounds__(256, 2) void attn2_k(
    const __half* __restrict__ qb, const __half* __restrict__ vb,
    const __half* __restrict__ udl, const __half* __restrict__ cbh,
    const __half* __restrict__ xlrh, const float* __restrict__ biasv,
    const float* __restrict__ duv, const int* __restrict__ zb,
    const float* __restrict__ xlu, float* __restrict__ aout) {
  __shared__ __half quS[64][140];
  __shared__ __half KX[128][140];
  __shared__ __half VtS[64][140];
  __shared__ float duvS[128];
  __shared__ float biasS[64];

  const int tid = threadIdx.x;
  const int qt = blockIdx.x;
  const int b = blockIdx.y >> 3, r = blockIdx.y & 7;
  const int h = blockIdx.z;
  const int c0 = qt * 64;
  const int rowg = tid >> 4;
  const int colg = tid & 15;
  const size_t tokH = (size_t)h * (Bn * Tn) + (size_t)b * Tn;
  const int tBlk = r * Cn + c0;

  // stage qu = q + xl_u (f16)
  {
    const float* up = xlu + h * Kn;
    for (int idx = tid; idx < 64 * 128; idx += 256) {
      const int row = idx >> 7, d = idx & 127;
      const float qv = __half2float(qb[(tokH + tBlk + row) * Kn + d]);
      quS[row][d] = __float2half(qv + up[d]);
    }
  }

  float mR[4], lR[4], O[4][8];
#pragma unroll
  for (int i = 0; i < 4; ++i) {
    mR[i] = -NEGV;
    lR[i] = 0.f;
#pragma unroll
    for (int k = 0; k < 8; ++k) O[i][k] = 0.f;
  }

  for (int ch = 0; ch < 16; ++ch) {
    const bool isC = (ch < 8);
    const int rc = ch - 8;
    const int w0 = rc * 64;
    const int s0 = ch * 64;
    const int jbase = w0 + 192 - c0;
    __syncthreads();  // protect prior-chunk LDS reads (and qu stage at ch=0)
    if (isC) {
      for (int idx = tid; idx < 64 * 32; idx += 256) {
        const int row = idx >> 5, seg = (idx & 31) * 4;
        *(uint2*)&KX[row][seg] =
            *(const uint2*)&cbh[((size_t)h * Sn + s0 + row) * Kn + seg];
        *(uint2*)&VtS[row][seg] = *(const uint2*)&udl
            [((((size_t)h * Bn + b) * Rn + r) * Sn + s0 + row) * Vn + seg];
      }
      if (tid < 64)
        biasS[tid] = biasv[(((size_t)h * Bn + b) * Rn + r) * Sn + s0 + tid];
    } else {
      for (int idx = tid; idx < 64 * 32; idx += 256) {
        const int row = idx >> 5, seg = (idx & 31) * 4;
        int tk = (r - 1) * Cn + w0 + row;
        if (tk < 0) tk = 0;
        const int code = zb[tokH + tk];
        *(uint2*)&KX[row][seg] =
            *(const uint2*)&cbh[((size_t)h * Sn + code) * Kn + seg];
        *(uint2*)&VtS[row][seg] = *(const uint2*)&vb[(tokH + tk) * Kn + seg];
      }
      if (tid < 128) {
        int jx = jbase + tid;
        jx = jx < 0 ? 0 : (jx > Wn - 1 ? Wn - 1 : jx);
        duvS[tid] = duv[h * Wn + jx];
      }
    }
    __syncthreads();
    // ---- ac = qu . K ----
    float acc4[4][4] = {};
#pragma unroll 4
    for (int dp = 0; dp < 64; ++dp) {
      float2 av[4], bv[4];
#pragma unroll
      for (int i = 0; i < 4; ++i)
        av[i] = __half22float2(
            *reinterpret_cast<const __half2*>(&quS[rowg * 4 + i][2 * dp]));
#pragma unroll
      for (int j = 0; j < 4; ++j)
        bv[j] = __half22float2(
            *reinterpret_cast<const __half2*>(&KX[colg + 16 * j][2 * dp]));
#pragma unroll
      for (int i = 0; i < 4; ++i)
#pragma unroll
        for (int j = 0; j < 4; ++j)
          acc4[i][j] =
              fmaf(av[i].y, bv[j].y, fmaf(av[i].x, bv[j].x, acc4[i][j]));
    }
    float lg[4][4];
    if (isC) {
#pragma unroll
      for (int i = 0; i < 4; ++i)
#pragma unroll
        for (int j = 0; j < 4; ++j)
          lg[i][j] = acc4[i][j] * INV_TAU + biasS[colg + 16 * j];
    } else {
      __syncthreads();  // done with K rows; restage region with xlr
      for (int idx = tid; idx < 128 * 32; idx += 256) {
        const int row = idx >> 5, seg = (idx & 31) * 4;
        int jx = jbase + row;
        jx = jx < 0 ? 0 : (jx > Wn - 1 ? Wn - 1 : jx);
        *(uint2*)&KX[row][seg] =
            *(const uint2*)&xlrh[((size_t)h * Wn + jx) * Kn + seg];
      }
      __syncthreads();
      // ---- bd += qu . xlr[li] ----
#pragma unroll 2
      for (int dp = 0; dp < 64; ++dp) {
        float2 av[4];
#pragma unroll
        for (int i = 0; i < 4; ++i)
          av[i] = __half22float2(
              *reinterpret_cast<const __half2*>(&quS[rowg * 4 + i][2 * dp]));
#pragma unroll
        for (int i = 0; i < 4; ++i)
#pragma unroll
          for (int j = 0; j < 4; ++j) {
            const int li = colg + 16 * j + 63 - (rowg * 4 + i);
            const float2 xv = __half22float2(
                *reinterpret_cast<const __half2*>(&KX[li][2 * dp]));
            acc4[i][j] =
                fmaf(av[i].y, xv.y, fmaf(av[i].x, xv.x, acc4[i][j]));
          }
      }
#pragma unroll
      for (int i = 0; i < 4; ++i) {
        const int cl = rowg * 4 + i;
#pragma unroll
        for (int j = 0; j < 4; ++j) {
          const int w = w0 + colg + 16 * j;
          const int li = colg + 16 * j + 63 - cl;
          const bool valid = (w <= cl + c0 + Cn) && !(r == 0 && w < Cn);
          lg[i][j] = valid ? (acc4[i][j] + duvS[li]) * INV_TAU : -NEGV;
        }
      }
    }
    // ---- online softmax (rows owned by rowg; reduce over 16 colg lanes) ----
    float p[4][4];
#pragma unroll
    for (int i = 0; i < 4; ++i) {
      float rm = fmaxf(fmaxf(lg[i][0], lg[i][1]), fmaxf(lg[i][2], lg[i][3]));
      rm = fmaxf(rm, __shfl_xor(rm, 1));
      rm = fmaxf(rm, __shfl_xor(rm, 2));
      rm = fmaxf(rm, __shfl_xor(rm, 4));
      rm = fmaxf(rm, __shfl_xor(rm, 8));
      const float mn = fmaxf(mR[i], rm);
      const float sc = __expf(mR[i] - mn);
      float rs = 0.f;
#pragma unroll
      for (int j = 0; j < 4; ++j) {
        p[i][j] = __expf(lg[i][j] - mn);
        rs += p[i][j];
      }
      rs += __shfl_xor(rs, 1);
      rs += __shfl_xor(rs, 2);
      rs += __shfl_xor(rs, 4);
      rs += __shfl_xor(rs, 8);
      lR[i] = lR[i] * sc + rs;
      mR[i] = mn;
#pragma unroll
      for (int k = 0; k < 8; ++k) O[i][k] *= sc;
    }
    // ---- PV: col = s4*16 + j4 owned by lane (rowg,colg=j4) slot s4 ----
    for (int j4 = 0; j4 < 16; ++j4) {
      const int addr = (((tid & 0x30) | j4) << 2);
#pragma unroll
      for (int s4 = 0; s4 < 4; ++s4) {
        const int col = s4 * 16 + j4;
        float pj[4];
#pragma unroll
        for (int i = 0; i < 4; ++i)
          pj[i] = __int_as_float(
              __builtin_amdgcn_ds_bpermute(addr, __float_as_int(p[i][s4])));
#pragma unroll
        for (int k2 = 0; k2 < 4; ++k2) {
          const float2 fv = __half22float2(
              *reinterpret_cast<const __half2*>(&VtS[col][colg * 8 + 2 * k2]));
#pragma unroll
          for (int i = 0; i < 4; ++i) {
            O[i][2 * k2] = fmaf(pj[i], fv.x, O[i][2 * k2]);
            O[i][2 * k2 + 1] = fmaf(pj[i], fv.y, O[i][2 * k2 + 1]);
          }
        }
      }
    }
  }
  // ---- write out: aout[b*T + t][h*128 + d] ----
#pragma unroll
  for (int i = 0; i < 4; ++i) {
    const float inv = 1.0f / lR[i];
    float* op = aout + ((size_t)b * Tn + tBlk + rowg * 4 + i) * (Hn * Vn) +
                h * Vn + colg * 8;
    *reinterpret_cast<float4*>(&op[0]) =
        make_float4(O[i][0] * inv, O[i][1] * inv, O[i][2] * inv, O[i][3] * inv);
    *reinterpret_cast<float4*>(&op[4]) =
        make_float4(O[i][4] * inv, O[i][5] * inv, O[i][6] * inv, O[i][7] * inv);
  }
}

// ---------------- launcher ----------------
extern "C" void kernel_launch(void* const* d_in, const int* in_sizes, int n_in,
                              void* d_out, int out_size, void* d_ws,
                              size_t ws_size, hipStream_t stream) {
  (void)in_sizes;
  (void)n_in;
  (void)out_size;
  const float* x = (const float*)d_in[0];
  const float* g_ln = (const float*)d_in[1];
  const float* Wq = (const float*)d_in[2];
  const float* Wk = (const float*)d_in[3];
  const float* Wv = (const float*)d_in[4];
  const float* cb = (const float*)d_in[5];
  const float* xl_r = (const float*)d_in[6];
  const float* xl_u = (const float*)d_in[7];
  const float* xl_v = (const float*)d_in[8];
  const float* Wo = (const float*)d_in[9];
  float* out = (float*)d_out;

  float* W = (float*)d_ws;
  size_t o = 0;
  float* xt = W + o;                                // region1: xt, later udl
  __half* udlh = (__half*)xt;
  o += (size_t)Bn * Tn * Dn;                        // 8,388,608
  float* kb = W + o;                                // region2: kb, later aout
  float* aout = kb;
  o += (size_t)Hn * Bn * Tn * Kn;                   // 8,388,608
  __half* qbh = (__half*)(W + o);
  o += (size_t)Hn * Bn * Tn * Kn / 2;               // 4,194,304
  __half* vbh = (__half*)(W + o);
  o += (size_t)Hn * Bn * Tn * Vn / 2;               // 4,194,304
  __half* cbh = (__half*)(W + o);
  o += (size_t)Hn * Sn * Kn / 2;                    // 262,144
  __half* xlrh = (__half*)(W + o);
  o += (size_t)Hn * Wn * Kn / 2;                    // 262,144
  int* zb = (int*)(W + o);
  o += (size_t)Hn * Bn * Tn;                        // 65,536
  float* biasb = W + o;
  o += (size_t)Hn * Bn * Rn * Sn;                   // 131,072
  float* duvb = W + o;
  o += (size_t)Hn * Wn;                             // 4,096
  float* cb2b = W + o;
  o += (size_t)Hn * Sn;                             // 4,096

  if (ws_size < o * sizeof(float)) return;  // bail visibly if ws too small

  rmsnorm_k<<<Bn * Tn, 256, 0, stream>>>(x, g_ln, xt);
  cb2_k<<<Hn * Sn / 256, 256, 0, stream>>>(cb, cb2b);
  cvt_k<<<2 * Hn * Sn * Kn / 256, 256, 0, stream>>>(cb, xl_r, cbh, xlrh);
  duv_k<<<Hn, 256, 0, stream>>>(xl_r, xl_u, xl_v, duvb);

  // projections (batched, all heads)
  gemm_k<0><<<dim3(64, 8), 256, 0, stream>>>(xt, Wk, kb, 8192, 1024, 1024,
                                             1024);
  gemm_k<4><<<dim3(64, 8), 256, 0, stream>>>(xt, Wq, qbh, 8192, 1024, 1024,
                                             1024);
  gemm_k<4><<<dim3(64, 8), 256, 0, stream>>>(xt, Wv, vbh, 8192, 1024, 1024,
                                             1024);

  argmin2_k<<<dim3(Bn * Tn / 128, Hn), 256, 0, stream>>>(kb, cb, cb2b, zb);
  scan_k<<<dim3(4, Bn, Hn), 256, 0, stream>>>(zb, vbh, udlh, biasb);

  attn2_k<<<dim3(4, Bn * Rn, Hn), 256, 0, stream>>>(
      qbh, vbh, udlh, cbh, xlrh, biasb, duvb, zb, xl_u, aout);

  gemm_k<1><<<dim3(64, 8), 256, 0, stream>>>(aout, Wo, out, 8192, 1024, 1024,
                                             1024);
}

// Round 4
// 776.816 us; speedup vs baseline: 7.7264x; 2.6097x over previous
//
#include <hip/hip_runtime.h>
#include <hip/hip_fp16.h>

typedef _Float16 half8 __attribute__((ext_vector_type(8)));
typedef float f32x4 __attribute__((ext_vector_type(4)));

constexpr int Bn = 4, Tn = 2048, Dn = 1024, Hn = 8, Kn = 128, Vn = 128;
constexpr int Sn = 512, Cn = 256, Rn = 8, Wn = 512;
constexpr float NEGV = 1.0e30f;
constexpr float INV_TAU = 0.08838834764831845f;  // 1/sqrt(128)

__device__ __forceinline__ half8 ldh8(const __half* p) {
  return *reinterpret_cast<const half8*>(p);
}
__device__ __forceinline__ void sth8(__half* p, half8 v) {
  *reinterpret_cast<half8*>(p) = v;
}
__device__ __forceinline__ f32x4 mfma16(half8 a, half8 b, f32x4 c) {
  return __builtin_amdgcn_mfma_f32_16x16x32_f16(a, b, c, 0, 0, 0);
}

// ---------------- RMSNorm -> scale s[t] + f16 xth ----------------
__global__ __launch_bounds__(256) void rms2_k(const float* __restrict__ x,
                                              const float* __restrict__ g,
                                              __half* __restrict__ xth,
                                              float* __restrict__ s) {
  const int row = blockIdx.x;
  const int tid = threadIdx.x;
  const float4 v = reinterpret_cast<const float4*>(x + (size_t)row * Dn)[tid];
  float ss = v.x * v.x + v.y * v.y + v.z * v.z + v.w * v.w;
#pragma unroll
  for (int o = 32; o > 0; o >>= 1) ss += __shfl_xor(ss, o);
  __shared__ float red[4];
  if ((tid & 63) == 0) red[tid >> 6] = ss;
  __syncthreads();
  const float tot = red[0] + red[1] + red[2] + red[3];
  const float sc = rsqrtf(tot * (1.0f / Dn) + 1e-6f);
  if (tid == 0) s[row] = sc;
  const float4 gv = reinterpret_cast<const float4*>(g)[tid];
  __half2* op = reinterpret_cast<__half2*>(xth + (size_t)row * Dn + tid * 4);
  op[0] = __floats2half2_rn(v.x * sc * gv.x, v.y * sc * gv.y);
  op[1] = __floats2half2_rn(v.z * sc * gv.z, v.w * sc * gv.w);
}

// ---------------- Wk' = g (x) Wk  (f32) ----------------
__global__ __launch_bounds__(256) void wkp_k(const float* __restrict__ wk,
                                             const float* __restrict__ g,
                                             float* __restrict__ wkp) {
  const int i = blockIdx.x * 256 + threadIdx.x;
  wkp[i] = g[i >> 10] * wk[i];
}

// ---------------- transpose + f32->f16: dst[n][d] = src[d][n], 1024x1024 ---
__global__ __launch_bounds__(256) void transcvt_k(const float* __restrict__ src,
                                                  __half* __restrict__ dst) {
  __shared__ float ts[32][33];
  const int bx = blockIdx.x, by = blockIdx.y;
  const int j = threadIdx.x & 31, i0 = threadIdx.x >> 5;
#pragma unroll
  for (int rr = 0; rr < 4; ++rr) {
    const int row = i0 + rr * 8;
    ts[row][j] = src[(size_t)(by * 32 + row) * 1024 + bx * 32 + j];
  }
  __syncthreads();
#pragma unroll
  for (int rr = 0; rr < 4; ++rr) {
    const int row = i0 + rr * 8;
    dst[(size_t)(bx * 32 + row) * 1024 + by * 32 + j] = __float2half(ts[j][row]);
  }
}

// ---------------- codebook squared norms ----------------
__global__ __launch_bounds__(256) void cb2_k(const float* __restrict__ cb,
                                             float* __restrict__ cb2v) {
  const int idx = blockIdx.x * 256 + threadIdx.x;  // < H*S
  const float4* rp = reinterpret_cast<const float4*>(cb + (size_t)idx * Kn);
  float ss = 0.f;
#pragma unroll 8
  for (int i = 0; i < Kn / 4; ++i) {
    const float4 v = rp[i];
    ss += v.x * v.x + v.y * v.y + v.z * v.z + v.w * v.w;
  }
  cb2v[idx] = ss;
}

// ---------------- f32 -> f16 conversion (cb and xl_r) ----------------
__global__ __launch_bounds__(256) void cvt_k(const float* __restrict__ cb,
                                             const float* __restrict__ xlr,
                                             __half* __restrict__ cbh,
                                             __half* __restrict__ xlrh) {
  const int i = blockIdx.x * 256 + threadIdx.x;
  constexpr int NE = Hn * Sn * Kn;  // 524288
  if (i < NE)
    cbh[i] = __float2half(cb[i]);
  else
    xlrh[i - NE] = __float2half(xlr[i - NE]);
}

// ---------------- duv[h][j] = (xl_v - xl_u) . xl_r[h][j] ----------------
__global__ __launch_bounds__(256) void duv_k(const float* __restrict__ xlr,
                                             const float* __restrict__ xlu,
                                             const float* __restrict__ xlv,
                                             float* __restrict__ duv) {
  const int h = blockIdx.x;
  const float* up = xlu + h * Kn;
  const float* vp = xlv + h * Kn;
  for (int j = threadIdx.x; j < Wn; j += 256) {
    const float* rp = xlr + ((size_t)h * Wn + j) * Kn;
    float s = 0.f;
#pragma unroll 8
    for (int d = 0; d < Kn; ++d) s = fmaf(vp[d] - up[d], rp[d], s);
    duv[h * Wn + j] = s;
  }
}

// ------------- f32 NN GEMM (k-projection), out = s[m] * (x.Wkp), remap -----
__global__ __launch_bounds__(256, 2) void gemmf_k(const float* __restrict__ A,
                                                  const float* __restrict__ Bw,
                                                  float* __restrict__ Cout,
                                                  const float* __restrict__ s,
                                                  int M, int N, int KD) {
  __shared__ float As[16][132];
  __shared__ float Bs[16][132];
  const int tid = threadIdx.x;
  const int m0 = blockIdx.x * 128;
  const int n0 = blockIdx.y * 128;
  const int lr = tid >> 2, lc4 = (tid & 3) * 4;
  const int bkr = tid >> 5, bj4 = (tid & 31) * 4;

  auto ldA = [&](int kt, int half_) {
    return *reinterpret_cast<const float4*>(
        &A[(size_t)(m0 + lr + half_ * 64) * KD + kt + lc4]);
  };
  auto ldB = [&](int kt, int half_) {
    return *reinterpret_cast<const float4*>(
        &Bw[(size_t)(kt + bkr + half_ * 8) * N + n0 + bj4]);
  };

  float4 pa0 = ldA(0, 0), pa1 = ldA(0, 1);
  float4 pb0 = ldB(0, 0), pb1 = ldB(0, 1);

  float acc[8][8] = {};
  const int mr = (tid >> 4) * 8;
  const int nr = (tid & 15) * 8;

  for (int kt = 0; kt < KD; kt += 16) {
    __syncthreads();
    As[lc4 + 0][lr] = pa0.x;
    As[lc4 + 1][lr] = pa0.y;
    As[lc4 + 2][lr] = pa0.z;
    As[lc4 + 3][lr] = pa0.w;
    As[lc4 + 0][lr + 64] = pa1.x;
    As[lc4 + 1][lr + 64] = pa1.y;
    As[lc4 + 2][lr + 64] = pa1.z;
    As[lc4 + 3][lr + 64] = pa1.w;
    *reinterpret_cast<float4*>(&Bs[bkr][bj4]) = pb0;
    *reinterpret_cast<float4*>(&Bs[bkr + 8][bj4]) = pb1;
    __syncthreads();
    if (kt + 16 < KD) {
      pa0 = ldA(kt + 16, 0);
      pa1 = ldA(kt + 16, 1);
      pb0 = ldB(kt + 16, 0);
      pb1 = ldB(kt + 16, 1);
    }
#pragma unroll
    for (int c = 0; c < 16; ++c) {
      float a[8], bv[8];
#pragma unroll
      for (int i = 0; i < 8; ++i) {
        a[i] = As[c][mr + i];
        bv[i] = Bs[c][nr + i];
      }
#pragma unroll
      for (int i = 0; i < 8; ++i)
#pragma unroll
        for (int j = 0; j < 8; ++j) acc[i][j] = fmaf(a[i], bv[j], acc[i][j]);
    }
  }
  // remap to [head = n0>>7][m][128], scaled by s[m]
  float* O = Cout + (size_t)(n0 >> 7) * M * 128;
#pragma unroll
  for (int i = 0; i < 8; ++i) {
    const float sv = s[m0 + mr + i];
    const size_t ro = (size_t)(m0 + mr + i) * 128 + nr;
    *reinterpret_cast<float4*>(&O[ro]) =
        make_float4(acc[i][0] * sv, acc[i][1] * sv, acc[i][2] * sv,
                    acc[i][3] * sv);
    *reinterpret_cast<float4*>(&O[ro + 4]) =
        make_float4(acc[i][4] * sv, acc[i][5] * sv, acc[i][6] * sv,
                    acc[i][7] * sv);
  }
}

// ------------- f16 MFMA NT GEMM: C[m][n] = sum_k A[m][k] * Bt[n][k] --------
// MODE 0: f16 out remapped [h = n0>>7][m][128]   (q/v projections)
// MODE 1: f32 out row-major [M][N]               (output projection)
template <int MODE>
__global__ __launch_bounds__(256, 4) void gemmh_k(const __half* __restrict__ A,
                                                  const __half* __restrict__ Bt,
                                                  void* __restrict__ Cout,
                                                  int M, int N, int KD) {
  __shared__ __half As[128 * 72];
  __shared__ __half Bs[128 * 72];
  const int tid = threadIdx.x;
  const int lane = tid & 63, wq = tid >> 6;
  const int lrow = lane & 15, lk8 = (lane >> 4) << 3;
  const int m0 = blockIdx.x * 128, n0 = blockIdx.y * 128;
  const int srow = tid >> 2, spart = tid & 3;

  f32x4 acc[2][8];
#pragma unroll
  for (int mt = 0; mt < 2; ++mt)
#pragma unroll
    for (int nt = 0; nt < 8; ++nt) acc[mt][nt] = (f32x4){0.f, 0.f, 0.f, 0.f};

  for (int kt = 0; kt < KD; kt += 64) {
    __syncthreads();
#pragma unroll
    for (int hh = 0; hh < 2; ++hh) {
      const int row = srow + hh * 64;
      const __half* pa = A + (size_t)(m0 + row) * KD + kt + spart * 16;
      const __half* pb = Bt + (size_t)(n0 + row) * KD + kt + spart * 16;
      sth8(&As[row * 72 + spart * 16], ldh8(pa));
      sth8(&As[row * 72 + spart * 16 + 8], ldh8(pa + 8));
      sth8(&Bs[row * 72 + spart * 16], ldh8(pb));
      sth8(&Bs[row * 72 + spart * 16 + 8], ldh8(pb + 8));
    }
    __syncthreads();
#pragma unroll
    for (int ks = 0; ks < 2; ++ks) {
      half8 a0 = ldh8(&As[(32 * wq + lrow) * 72 + lk8 + 32 * ks]);
      half8 a1 = ldh8(&As[(32 * wq + 16 + lrow) * 72 + lk8 + 32 * ks]);
#pragma unroll
      for (int nt = 0; nt < 8; ++nt) {
        half8 b = ldh8(&Bs[(16 * nt + lrow) * 72 + lk8 + 32 * ks]);
        acc[0][nt] = mfma16(a0, b, acc[0][nt]);
        acc[1][nt] = mfma16(a1, b, acc[1][nt]);
      }
    }
  }
  if (MODE == 0) {
    __half* O = reinterpret_cast<__half*>(Cout) + (size_t)(n0 >> 7) * M * 128;
#pragma unroll
    for (int mt = 0; mt < 2; ++mt)
#pragma unroll
      for (int nt = 0; nt < 8; ++nt)
#pragma unroll
        for (int reg = 0; reg < 4; ++reg) {
          const int row = m0 + 32 * wq + 16 * mt + 4 * (lane >> 4) + reg;
          O[(size_t)row * 128 + 16 * nt + lrow] = __float2half(acc[mt][nt][reg]);
        }
  } else {
    float* O = reinterpret_cast<float*>(Cout);
#pragma unroll
    for (int mt = 0; mt < 2; ++mt)
#pragma unroll
      for (int nt = 0; nt < 8; ++nt)
#pragma unroll
        for (int reg = 0; reg < 4; ++reg) {
          const int row = m0 + 32 * wq + 16 * mt + 4 * (lane >> 4) + reg;
          O[(size_t)row * N + n0 + 16 * nt + lrow] = acc[mt][nt][reg];
        }
  }
}

// ---------------- fused dot + argmin (all heads, f32) ----------------
__global__ __launch_bounds__(256, 2) void argmin2_k(
    const float* __restrict__ kb, const float* __restrict__ cb,
    const float* __restrict__ cb2v, int* __restrict__ zb) {
  __shared__ float As[16][132];
  __shared__ float Bs[16][132];
  const int tid = threadIdx.x;
  const int m0 = blockIdx.x * 128;
  const int h = blockIdx.y;
  const float* Ab = kb + (size_t)h * (Bn * Tn) * Kn;
  const float* Bb = cb + (size_t)h * Sn * Kn;
  const int lr = tid >> 2, lc4 = (tid & 3) * 4;
  const int mr = (tid >> 4) * 8, nr = (tid & 15) * 8;
  float best[8];
  int bidx[8];
#pragma unroll
  for (int i = 0; i < 8; ++i) {
    best[i] = 3.0e38f;
    bidx[i] = 0;
  }
  for (int s0 = 0; s0 < Sn; s0 += 128) {
    float acc[8][8] = {};
    for (int kt = 0; kt < Kn; kt += 16) {
      __syncthreads();
      {
        const float4 a0 = *reinterpret_cast<const float4*>(
            &Ab[(size_t)(m0 + lr) * Kn + kt + lc4]);
        const float4 a1 = *reinterpret_cast<const float4*>(
            &Ab[(size_t)(m0 + lr + 64) * Kn + kt + lc4]);
        const float4 b0 = *reinterpret_cast<const float4*>(
            &Bb[(size_t)(s0 + lr) * Kn + kt + lc4]);
        const float4 b1 = *reinterpret_cast<const float4*>(
            &Bb[(size_t)(s0 + lr + 64) * Kn + kt + lc4]);
        As[lc4 + 0][lr] = a0.x;
        As[lc4 + 1][lr] = a0.y;
        As[lc4 + 2][lr] = a0.z;
        As[lc4 + 3][lr] = a0.w;
        As[lc4 + 0][lr + 64] = a1.x;
        As[lc4 + 1][lr + 64] = a1.y;
        As[lc4 + 2][lr + 64] = a1.z;
        As[lc4 + 3][lr + 64] = a1.w;
        Bs[lc4 + 0][lr] = b0.x;
        Bs[lc4 + 1][lr] = b0.y;
        Bs[lc4 + 2][lr] = b0.z;
        Bs[lc4 + 3][lr] = b0.w;
        Bs[lc4 + 0][lr + 64] = b1.x;
        Bs[lc4 + 1][lr + 64] = b1.y;
        Bs[lc4 + 2][lr + 64] = b1.z;
        Bs[lc4 + 3][lr + 64] = b1.w;
      }
      __syncthreads();
#pragma unroll
      for (int c = 0; c < 16; ++c) {
        float a[8], bv[8];
#pragma unroll
        for (int i = 0; i < 8; ++i) {
          a[i] = As[c][mr + i];
          bv[i] = Bs[c][nr + i];
        }
#pragma unroll
        for (int i = 0; i < 8; ++i)
#pragma unroll
          for (int j = 0; j < 8; ++j) acc[i][j] = fmaf(a[i], bv[j], acc[i][j]);
      }
    }
#pragma unroll
    for (int i = 0; i < 8; ++i)
#pragma unroll
      for (int j = 0; j < 8; ++j) {
        const float d2 = cb2v[h * Sn + s0 + nr + j] - 2.0f * acc[i][j];
        if (d2 < best[i]) {
          best[i] = d2;
          bidx[i] = s0 + nr + j;
        }
      }
  }
#pragma unroll
  for (int xb = 1; xb <= 8; xb <<= 1) {
#pragma unroll
    for (int i = 0; i < 8; ++i) {
      const float ob = __shfl_xor(best[i], xb);
      const int oi = __shfl_xor(bidx[i], xb);
      if (ob < best[i] || (ob == best[i] && oi < bidx[i])) {
        best[i] = ob;
        bidx[i] = oi;
      }
    }
  }
  if ((tid & 15) == 0) {
#pragma unroll
    for (int i = 0; i < 8; ++i)
      zb[(size_t)h * (Bn * Tn) + m0 + mr + i] = bidx[i];
  }
}

// ------- scan: cumulative cluster stats -> udl (f16) + bias, LDS-local -----
__global__ __launch_bounds__(256) void scan_k(const int* __restrict__ zb,
                                              const __half* __restrict__ vb,
                                              __half* __restrict__ udl,
                                              float* __restrict__ biasv) {
  __shared__ float acc[128][128];
  __shared__ float cnt[128];
  const int tid = threadIdx.x;
  const int sc = blockIdx.x, b = blockIdx.y, h = blockIdx.z;
  const int s0 = sc * 128;
  for (int i = tid; i < 128 * 128; i += 256) acc[i >> 7][i & 127] = 0.f;
  if (tid < 128) cnt[tid] = 0.f;
  __syncthreads();
  const size_t tokH = (size_t)h * (Bn * Tn) + (size_t)b * Tn;
  const int dd = tid & 127, halfh = tid >> 7;
  for (int r = 0; r < Rn; ++r) {
    for (int i = tid; i < 128 * 128; i += 256) {
      const int srow = i >> 7, d = i & 127;
      const float c = cnt[srow];
      const float v = acc[srow][d] / fmaxf(c, 1.f);
      udl[((((size_t)h * Bn + b) * Rn + r) * Sn + s0 + srow) * Vn + d] =
          __float2half(v);
    }
    if (tid < 128) {
      const float c = cnt[tid];
      biasv[(((size_t)h * Bn + b) * Rn + r) * Sn + s0 + tid] =
          (c > 0.f) ? logf(c) : -NEGV;
    }
    __syncthreads();
    if (r >= 1 && r < 7) {
      const int tb = (r - 1) * Cn;
#pragma unroll 4
      for (int u = 0; u < 128; ++u) {
        const int tok = tb + u * 2 + halfh;
        const int s = zb[tokH + tok];
        if (s >= s0 && s < s0 + 128) {
          const float v = __half2float(vb[(tokH + tok) * Vn + dd]);
          atomicAdd(&acc[s - s0][dd], v);
          if (dd == 0) atomicAdd(&cnt[s - s0], 1.0f);
        }
      }
    }
    __syncthreads();
  }
}

// ---------------- MFMA fused attention ----------------
__global__ __launch_bounds__(256, 2) void attn3_k(
    const __half* __restrict__ qbh, const __half* __restrict__ vbh,
    const __half* __restrict__ udl, const __half* __restrict__ cbh,
    const __half* __restrict__ xlrh, const float* __restrict__ biasv,
    const float* __restrict__ duv, const int* __restrict__ zb,
    const float* __restrict__ xlu, __half* __restrict__ aout) {
  __shared__ __half quS[64 * 136];
  __shared__ __half KXS[64 * 136];
  __shared__ __half VtS[128 * 72];
  __shared__ __half PBD[64 * 136];
  __shared__ float duvS[128];
  __shared__ float biasS[64];

  const int tid = threadIdx.x;
  const int lane = tid & 63, wq = tid >> 6;
  const int lrow = lane & 15, lk8 = (lane >> 4) << 3;
  const int qt = blockIdx.x;
  const int b = blockIdx.y >> 3, r = blockIdx.y & 7;
  const int h = blockIdx.z;
  const int c0 = qt * 64;
  const int tBlk = r * Cn + c0;
  const size_t tokH = (size_t)h * (Bn * Tn) + (size_t)b * Tn;
  const size_t sBase = (((size_t)h * Bn + b) * Rn + r) * Sn;
  const int srow = tid >> 2, spart = tid & 3;   // 64-row staging
  const int kp = tid >> 3, p8 = tid & 7;        // Vt staging

  // stage quS = q + xl_u
  {
    const __half* src = qbh + (tokH + tBlk + srow) * Kn + spart * 32;
    const float* up = xlu + h * Kn + spart * 32;
    alignas(16) __half tmp[32];
#pragma unroll
    for (int e = 0; e < 32; ++e)
      tmp[e] = __float2half(__half2float(src[e]) + up[e]);
#pragma unroll
    for (int g2 = 0; g2 < 4; ++g2)
      sth8(&quS[srow * 136 + spart * 32 + g2 * 8],
           *reinterpret_cast<half8*>(&tmp[g2 * 8]));
  }

  float mR[4], lR[4];
  f32x4 Oacc[8];
#pragma unroll
  for (int i = 0; i < 4; ++i) {
    mR[i] = -NEGV;
    lR[i] = 0.f;
  }
#pragma unroll
  for (int nt = 0; nt < 8; ++nt) Oacc[nt] = (f32x4){0.f, 0.f, 0.f, 0.f};

  half8 a[4];
  bool aLoaded = false;

  for (int ch = 0; ch < 16; ++ch) {
    const bool isC = (ch < 8);
    const int s0 = ch * 64;
    const int w0 = (ch - 8) * 64;
    const int jbase = w0 + 192 - c0;
    __syncthreads();  // (1) prior chunk's LDS reads complete
    if (isC) {
      const __half* ks = cbh + ((size_t)h * Sn + s0 + srow) * Kn + spart * 32;
      sth8(&KXS[srow * 136 + spart * 32], ldh8(ks));
      sth8(&KXS[srow * 136 + spart * 32 + 8], ldh8(ks + 8));
      sth8(&KXS[srow * 136 + spart * 32 + 16], ldh8(ks + 16));
      sth8(&KXS[srow * 136 + spart * 32 + 24], ldh8(ks + 24));
      const __half* u0 = udl + (sBase + s0 + 2 * kp) * Vn + p8 * 16;
      const __half* u1 = u0 + Vn;
#pragma unroll
      for (int e = 0; e < 16; ++e) {
        const int d = p8 * 16 + e;
        const int gidx = ((2 * kp) >> 3) ^ ((d >> 4) & 7);
        *reinterpret_cast<__half2*>(
            &VtS[d * 72 + gidx * 8 + ((2 * kp) & 7)]) =
            __halves2half2(u0[e], u1[e]);
      }
      if (tid < 64) biasS[tid] = biasv[sBase + s0 + tid];
    } else {
      int tk = (r - 1) * Cn + w0 + srow;
      if (tk < 0) tk = 0;
      const int code = zb[tokH + tk];
      const __half* ks = cbh + ((size_t)h * Sn + code) * Kn + spart * 32;
      sth8(&KXS[srow * 136 + spart * 32], ldh8(ks));
      sth8(&KXS[srow * 136 + spart * 32 + 8], ldh8(ks + 8));
      sth8(&KXS[srow * 136 + spart * 32 + 16], ldh8(ks + 16));
      sth8(&KXS[srow * 136 + spart * 32 + 24], ldh8(ks + 24));
      const int tk0 = (r - 1) * Cn + w0 + 2 * kp;
      const int tka = tk0 < 0 ? 0 : tk0;
      const int tkb = tk0 + 1 < 0 ? 0 : tk0 + 1;
      const __half* v0 = vbh + (tokH + tka) * Kn + p8 * 16;
      const __half* v1 = vbh + (tokH + tkb) * Kn + p8 * 16;
#pragma unroll
      for (int e = 0; e < 16; ++e) {
        const int d = p8 * 16 + e;
        const int gidx = ((2 * kp) >> 3) ^ ((d >> 4) & 7);
        *reinterpret_cast<__half2*>(
            &VtS[d * 72 + gidx * 8 + ((2 * kp) & 7)]) =
            __halves2half2(v0[e], v1[e]);
      }
    }
    __syncthreads();  // (3) staged data visible
    if (!aLoaded) {
#pragma unroll
      for (int ks = 0; ks < 4; ++ks)
        a[ks] = ldh8(&quS[(16 * wq + lrow) * 136 + lk8 + 32 * ks]);
      aLoaded = true;
    }
    // ---- ac = qu . K^T ----
    f32x4 acc[4];
#pragma unroll
    for (int nt = 0; nt < 4; ++nt) acc[nt] = (f32x4){0.f, 0.f, 0.f, 0.f};
#pragma unroll
    for (int ks = 0; ks < 4; ++ks)
#pragma unroll
      for (int nt = 0; nt < 4; ++nt)
        acc[nt] = mfma16(
            a[ks], ldh8(&KXS[(16 * nt + lrow) * 136 + lk8 + 32 * ks]),
            acc[nt]);

    float lg[4][4];  // [nt][reg]
    if (isC) {
#pragma unroll
      for (int nt = 0; nt < 4; ++nt) {
        const float bv = biasS[lrow + 16 * nt];
#pragma unroll
        for (int reg = 0; reg < 4; ++reg)
          lg[nt][reg] = acc[nt][reg] * INV_TAU + bv;
      }
    } else {
      // ---- bd: window GEMM qu . xlr^T in two 64-col halves ----
#pragma unroll
      for (int hh = 0; hh < 2; ++hh) {
        __syncthreads();  // KXS consumers done
        {
          int j = jbase + hh * 64 + srow;
          j = j < 0 ? 0 : (j > Wn - 1 ? Wn - 1 : j);
          const __half* xs = xlrh + ((size_t)h * Wn + j) * Kn + spart * 32;
          sth8(&KXS[srow * 136 + spart * 32], ldh8(xs));
          sth8(&KXS[srow * 136 + spart * 32 + 8], ldh8(xs + 8));
          sth8(&KXS[srow * 136 + spart * 32 + 16], ldh8(xs + 16));
          sth8(&KXS[srow * 136 + spart * 32 + 24], ldh8(xs + 24));
          if (hh == 0 && tid < 128) {
            int jx = jbase + tid;
            jx = jx < 0 ? 0 : (jx > Wn - 1 ? Wn - 1 : jx);
            duvS[tid] = duv[h * Wn + jx];
          }
        }
        __syncthreads();
        f32x4 bdh[4];
#pragma unroll
        for (int nt = 0; nt < 4; ++nt) bdh[nt] = (f32x4){0.f, 0.f, 0.f, 0.f};
#pragma unroll
        for (int ks = 0; ks < 4; ++ks)
#pragma unroll
          for (int nt = 0; nt < 4; ++nt)
            bdh[nt] = mfma16(
                a[ks], ldh8(&KXS[(16 * nt + lrow) * 136 + lk8 + 32 * ks]),
                bdh[nt]);
        // write bd (+duv) to PBD
#pragma unroll
        for (int nt = 0; nt < 4; ++nt) {
          const int col = hh * 64 + 16 * nt + lrow;
          const float dv = duvS[col];
#pragma unroll
          for (int reg = 0; reg < 4; ++reg) {
            const int row64 = 16 * wq + 4 * (lane >> 4) + reg;
            PBD[row64 * 136 + col] = __float2half(bdh[nt][reg] + dv);
          }
        }
      }
      __syncthreads();  // (14) bd values visible
#pragma unroll
      for (int nt = 0; nt < 4; ++nt) {
        const int key = lrow + 16 * nt;
        const int w = w0 + key;
#pragma unroll
        for (int reg = 0; reg < 4; ++reg) {
          const int row64 = 16 * wq + 4 * (lane >> 4) + reg;
          const bool valid = (w <= c0 + row64 + Cn) && !(r == 0 && w < Cn);
          const float bdv = __half2float(PBD[row64 * 136 + key + 63 - row64]);
          lg[nt][reg] = valid ? (acc[nt][reg] + bdv) * INV_TAU : -NEGV;
        }
      }
      __syncthreads();  // (16) bd reads done before P overwrite
    }
    // ---- online softmax (rows = 4*(lane>>4)+reg; reduce over 16 lanes) ----
    float p[4][4], scl[4];
#pragma unroll
    for (int reg = 0; reg < 4; ++reg) {
      float rm = fmaxf(fmaxf(lg[0][reg], lg[1][reg]),
                       fmaxf(lg[2][reg], lg[3][reg]));
      rm = fmaxf(rm, __shfl_xor(rm, 1));
      rm = fmaxf(rm, __shfl_xor(rm, 2));
      rm = fmaxf(rm, __shfl_xor(rm, 4));
      rm = fmaxf(rm, __shfl_xor(rm, 8));
      const float mn = fmaxf(mR[reg], rm);
      scl[reg] = __expf(mR[reg] - mn);
      float rs = 0.f;
#pragma unroll
      for (int nt = 0; nt < 4; ++nt) {
        p[nt][reg] = __expf(lg[nt][reg] - mn);
        rs += p[nt][reg];
      }
      rs += __shfl_xor(rs, 1);
      rs += __shfl_xor(rs, 2);
      rs += __shfl_xor(rs, 4);
      rs += __shfl_xor(rs, 8);
      lR[reg] = lR[reg] * scl[reg] + rs;
      mR[reg] = mn;
    }
#pragma unroll
    for (int nt = 0; nt < 8; ++nt)
#pragma unroll
      for (int reg = 0; reg < 4; ++reg) Oacc[nt][reg] *= scl[reg];
    // ---- write P (f16) ----
#pragma unroll
    for (int nt = 0; nt < 4; ++nt)
#pragma unroll
      for (int reg = 0; reg < 4; ++reg) {
        const int row64 = 16 * wq + 4 * (lane >> 4) + reg;
        PBD[row64 * 136 + lrow + 16 * nt] = __float2half(p[nt][reg]);
      }
    __syncthreads();  // (18)
    // ---- PV ----
#pragma unroll
    for (int ks = 0; ks < 2; ++ks) {
      half8 pa = ldh8(&PBD[(16 * wq + lrow) * 136 + lk8 + 32 * ks]);
#pragma unroll
      for (int nt = 0; nt < 8; ++nt) {
        const int gidx = (((lk8 + 32 * ks) >> 3) ^ nt);
        half8 vb = ldh8(&VtS[(16 * nt + lrow) * 72 + gidx * 8]);
        Oacc[nt] = mfma16(pa, vb, Oacc[nt]);
      }
    }
  }
  // ---- epilogue ----
  float inv[4];
#pragma unroll
  for (int reg = 0; reg < 4; ++reg) inv[reg] = 1.0f / lR[reg];
#pragma unroll
  for (int nt = 0; nt < 8; ++nt)
#pragma unroll
    for (int reg = 0; reg < 4; ++reg) {
      const int row64 = 16 * wq + 4 * (lane >> 4) + reg;
      aout[((size_t)b * Tn + tBlk + row64) * (Hn * Vn) + h * Vn + 16 * nt +
           lrow] = __float2half(Oacc[nt][reg] * inv[reg]);
    }
}

// ---------------- launcher ----------------
extern "C" void kernel_launch(void* const* d_in, const int* in_sizes, int n_in,
                              void* d_out, int out_size, void* d_ws,
                              size_t ws_size, hipStream_t stream) {
  (void)in_sizes;
  (void)n_in;
  (void)out_size;
  const float* x = (const float*)d_in[0];
  const float* g_ln = (const float*)d_in[1];
  const float* Wq = (const float*)d_in[2];
  const float* Wk = (const float*)d_in[3];
  const float* Wv = (const float*)d_in[4];
  const float* cb = (const float*)d_in[5];
  const float* xl_r = (const float*)d_in[6];
  const float* xl_u = (const float*)d_in[7];
  const float* xl_v = (const float*)d_in[8];
  const float* Wo = (const float*)d_in[9];
  float* out = (float*)d_out;

  float* W = (float*)d_ws;
  size_t o = 0;
  __half* xth = (__half*)(W + o);         // aliased later by aout (exact fit)
  __half* aout = xth;
  o += (size_t)Bn * Tn * Dn / 2;          // 4,194,304
  float* kb = W + o;                      // aliased later by udl (exact fit)
  __half* udlh = (__half*)kb;
  o += (size_t)Hn * Bn * Tn * Kn;         // 8,388,608
  __half* qbh = (__half*)(W + o);
  o += (size_t)Hn * Bn * Tn * Kn / 2;     // 2,097,152
  __half* vbh = (__half*)(W + o);
  o += (size_t)Hn * Bn * Tn * Vn / 2;     // 2,097,152
  __half* cbh = (__half*)(W + o);
  o += (size_t)Hn * Sn * Kn / 2;          // 131,072
  __half* xlrh = (__half*)(W + o);
  o += (size_t)Hn * Wn * Kn / 2;          // 131,072
  int* zb = (int*)(W + o);
  o += (size_t)Hn * Bn * Tn;              // 65,536
  float* biasb = W + o;
  o += (size_t)Hn * Bn * Rn * Sn;         // 131,072
  float* duvb = W + o;
  o += (size_t)Hn * Wn;                   // 4,096
  float* cb2b = W + o;
  o += (size_t)Hn * Sn;                   // 4,096
  float* wkp = W + o;
  o += (size_t)Dn * Dn;                   // 1,048,576
  __half* wqt = (__half*)(W + o);
  o += (size_t)Dn * Dn / 2;               // 524,288
  __half* wvt = (__half*)(W + o);
  o += (size_t)Dn * Dn / 2;
  __half* wot = (__half*)(W + o);
  o += (size_t)Dn * Dn / 2;
  float* sbuf = W + o;
  o += (size_t)Bn * Tn;                   // 8,192

  if (ws_size < o * sizeof(float)) return;  // bail visibly if ws too small

  rms2_k<<<Bn * Tn, 256, 0, stream>>>(x, g_ln, xth, sbuf);
  wkp_k<<<Dn * Dn / 256, 256, 0, stream>>>(Wk, g_ln, wkp);
  transcvt_k<<<dim3(32, 32), 256, 0, stream>>>(Wq, wqt);
  transcvt_k<<<dim3(32, 32), 256, 0, stream>>>(Wv, wvt);
  transcvt_k<<<dim3(32, 32), 256, 0, stream>>>(Wo, wot);
  cb2_k<<<Hn * Sn / 256, 256, 0, stream>>>(cb, cb2b);
  cvt_k<<<2 * Hn * Sn * Kn / 256, 256, 0, stream>>>(cb, xl_r, cbh, xlrh);
  duv_k<<<Hn, 256, 0, stream>>>(xl_r, xl_u, xl_v, duvb);

  // k-projection (f32 exact): kb[h][m][128] = s[m] * (x . (g*Wk))
  gemmf_k<<<dim3(64, 8), 256, 0, stream>>>(x, wkp, kb, sbuf, 8192, 1024, 1024);
  // q/v projections (f16 MFMA)
  gemmh_k<0><<<dim3(64, 8), 256, 0, stream>>>(xth, wqt, qbh, 8192, 1024, 1024);
  gemmh_k<0><<<dim3(64, 8), 256, 0, stream>>>(xth, wvt, vbh, 8192, 1024, 1024);

  argmin2_k<<<dim3(Bn * Tn / 128, Hn), 256, 0, stream>>>(kb, cb, cb2b, zb);
  scan_k<<<dim3(4, Bn, Hn), 256, 0, stream>>>(zb, vbh, udlh, biasb);

  attn3_k<<<dim3(4, Bn * Rn, Hn), 256, 0, stream>>>(
      qbh, vbh, udlh, cbh, xlrh, biasb, duvb, zb, xl_u, aout);

  // out = aout[B*T, H*V] . Wo  (f16 MFMA, f32 out)
  gemmh_k<1><<<dim3(64, 8), 256, 0, stream>>>(aout, wot, out, 8192, 1024,
                                              1024);
}

// Round 5
// 564.941 us; speedup vs baseline: 10.6242x; 1.3750x over previous
//
#include <hip/hip_runtime.h>
#include <hip/hip_fp16.h>

typedef _Float16 half8 __attribute__((ext_vector_type(8)));
typedef float f32x4 __attribute__((ext_vector_type(4)));

constexpr int Bn = 4, Tn = 2048, Dn = 1024, Hn = 8, Kn = 128, Vn = 128;
constexpr int Sn = 512, Cn = 256, Rn = 8, Wn = 512;
constexpr float NEGV = 1.0e30f;
constexpr float INV_TAU = 0.08838834764831845f;  // 1/sqrt(128)

__device__ __forceinline__ half8 ldh8(const __half* p) {
  return *reinterpret_cast<const half8*>(p);
}
__device__ __forceinline__ void sth8(__half* p, half8 v) {
  *reinterpret_cast<half8*>(p) = v;
}
__device__ __forceinline__ f32x4 mfma16(half8 a, half8 b, f32x4 c) {
  return __builtin_amdgcn_mfma_f32_16x16x32_f16(a, b, c, 0, 0, 0);
}

// ---------------- RMSNorm -> split f16 (hi + residual) ----------------
__global__ __launch_bounds__(256) void rms3_k(const float* __restrict__ x,
                                              const float* __restrict__ g,
                                              __half* __restrict__ xth,
                                              __half* __restrict__ xtl) {
  const int row = blockIdx.x;
  const int tid = threadIdx.x;
  const float4 v = reinterpret_cast<const float4*>(x + (size_t)row * Dn)[tid];
  float ss = v.x * v.x + v.y * v.y + v.z * v.z + v.w * v.w;
#pragma unroll
  for (int o = 32; o > 0; o >>= 1) ss += __shfl_xor(ss, o);
  __shared__ float red[4];
  if ((tid & 63) == 0) red[tid >> 6] = ss;
  __syncthreads();
  const float tot = red[0] + red[1] + red[2] + red[3];
  const float sc = rsqrtf(tot * (1.0f / Dn) + 1e-6f);
  const float4 gv = reinterpret_cast<const float4*>(g)[tid];
  float vv[4] = {v.x * sc * gv.x, v.y * sc * gv.y, v.z * sc * gv.z,
                 v.w * sc * gv.w};
  __half hi[4], lo[4];
#pragma unroll
  for (int e = 0; e < 4; ++e) {
    hi[e] = __float2half(vv[e]);
    lo[e] = __float2half(vv[e] - __half2float(hi[e]));
  }
  __half2* oph = reinterpret_cast<__half2*>(xth + (size_t)row * Dn + tid * 4);
  __half2* opl = reinterpret_cast<__half2*>(xtl + (size_t)row * Dn + tid * 4);
  oph[0] = __halves2half2(hi[0], hi[1]);
  oph[1] = __halves2half2(hi[2], hi[3]);
  opl[0] = __halves2half2(lo[0], lo[1]);
  opl[1] = __halves2half2(lo[2], lo[3]);
}

// ---------------- transpose + f32->f16: dst[n][d] = src[d][n] ----------------
__global__ __launch_bounds__(256) void transcvt_k(const float* __restrict__ src,
                                                  __half* __restrict__ dst) {
  __shared__ float ts[32][33];
  const int bx = blockIdx.x, by = blockIdx.y;
  const int j = threadIdx.x & 31, i0 = threadIdx.x >> 5;
#pragma unroll
  for (int rr = 0; rr < 4; ++rr) {
    const int row = i0 + rr * 8;
    ts[row][j] = src[(size_t)(by * 32 + row) * 1024 + bx * 32 + j];
  }
  __syncthreads();
#pragma unroll
  for (int rr = 0; rr < 4; ++rr) {
    const int row = i0 + rr * 8;
    dst[(size_t)(bx * 32 + row) * 1024 + by * 32 + j] = __float2half(ts[j][row]);
  }
}

// ------------- transpose + split f16 (hi + residual), for Wk ---------------
__global__ __launch_bounds__(256) void transcvt2_k(
    const float* __restrict__ src, __half* __restrict__ dh,
    __half* __restrict__ dl) {
  __shared__ float ts[32][33];
  const int bx = blockIdx.x, by = blockIdx.y;
  const int j = threadIdx.x & 31, i0 = threadIdx.x >> 5;
#pragma unroll
  for (int rr = 0; rr < 4; ++rr) {
    const int row = i0 + rr * 8;
    ts[row][j] = src[(size_t)(by * 32 + row) * 1024 + bx * 32 + j];
  }
  __syncthreads();
#pragma unroll
  for (int rr = 0; rr < 4; ++rr) {
    const int row = i0 + rr * 8;
    const float v = ts[j][row];
    const __half hi = __float2half(v);
    dh[(size_t)(bx * 32 + row) * 1024 + by * 32 + j] = hi;
    dl[(size_t)(bx * 32 + row) * 1024 + by * 32 + j] =
        __float2half(v - __half2float(hi));
  }
}

// ---------------- codebook squared norms ----------------
__global__ __launch_bounds__(256) void cb2_k(const float* __restrict__ cb,
                                             float* __restrict__ cb2v) {
  const int idx = blockIdx.x * 256 + threadIdx.x;  // < H*S
  const float4* rp = reinterpret_cast<const float4*>(cb + (size_t)idx * Kn);
  float ss = 0.f;
#pragma unroll 8
  for (int i = 0; i < Kn / 4; ++i) {
    const float4 v = rp[i];
    ss += v.x * v.x + v.y * v.y + v.z * v.z + v.w * v.w;
  }
  cb2v[idx] = ss;
}

// -------- f32 -> f16 conversion: cb (hi+lo) and xl_r (hi only) --------
__global__ __launch_bounds__(256) void cvt2_k(const float* __restrict__ cb,
                                              const float* __restrict__ xlr,
                                              __half* __restrict__ cbh,
                                              __half* __restrict__ cbl,
                                              __half* __restrict__ xlrh) {
  const int i = blockIdx.x * 256 + threadIdx.x;
  constexpr int NE = Hn * Sn * Kn;  // 524288
  if (i < NE) {
    const float v = cb[i];
    const __half hi = __float2half(v);
    cbh[i] = hi;
    cbl[i] = __float2half(v - __half2float(hi));
  } else {
    xlrh[i - NE] = __float2half(xlr[i - NE]);
  }
}

// ---------------- duv[h][j] = (xl_v - xl_u) . xl_r[h][j] ----------------
__global__ __launch_bounds__(256) void duv_k(const float* __restrict__ xlr,
                                             const float* __restrict__ xlu,
                                             const float* __restrict__ xlv,
                                             float* __restrict__ duv) {
  const int h = blockIdx.x;
  const float* up = xlu + h * Kn;
  const float* vp = xlv + h * Kn;
  for (int j = threadIdx.x; j < Wn; j += 256) {
    const float* rp = xlr + ((size_t)h * Wn + j) * Kn;
    float s = 0.f;
#pragma unroll 8
    for (int d = 0; d < Kn; ++d) s = fmaf(vp[d] - up[d], rp[d], s);
    duv[h * Wn + j] = s;
  }
}

// ------- split-f16 MFMA k-projection: k = (xh+xl).(wh+wl), 3 terms ---------
__global__ __launch_bounds__(256, 2) void kproj_k(
    const __half* __restrict__ Ah, const __half* __restrict__ Al,
    const __half* __restrict__ Bh, const __half* __restrict__ Bl,
    __half* __restrict__ Ch, __half* __restrict__ Cl, int M, int KD) {
  __shared__ __half AsH[128 * 72];
  __shared__ __half AsL[128 * 72];
  __shared__ __half BsH[128 * 72];
  __shared__ __half BsL[128 * 72];
  const int tid = threadIdx.x;
  const int lane = tid & 63, wq = tid >> 6;
  const int lrow = lane & 15, lk8 = (lane >> 4) << 3;
  const int m0 = blockIdx.x * 128, n0 = blockIdx.y * 128;
  const int srow = tid >> 2, spart = tid & 3;

  f32x4 acc[2][8];
#pragma unroll
  for (int mt = 0; mt < 2; ++mt)
#pragma unroll
    for (int nt = 0; nt < 8; ++nt) acc[mt][nt] = (f32x4){0.f, 0.f, 0.f, 0.f};

  for (int kt = 0; kt < KD; kt += 64) {
    __syncthreads();
#pragma unroll
    for (int hh = 0; hh < 2; ++hh) {
      const int row = srow + hh * 64;
      const size_t ao = (size_t)(m0 + row) * KD + kt + spart * 16;
      const size_t bo = (size_t)(n0 + row) * KD + kt + spart * 16;
      sth8(&AsH[row * 72 + spart * 16], ldh8(Ah + ao));
      sth8(&AsH[row * 72 + spart * 16 + 8], ldh8(Ah + ao + 8));
      sth8(&AsL[row * 72 + spart * 16], ldh8(Al + ao));
      sth8(&AsL[row * 72 + spart * 16 + 8], ldh8(Al + ao + 8));
      sth8(&BsH[row * 72 + spart * 16], ldh8(Bh + bo));
      sth8(&BsH[row * 72 + spart * 16 + 8], ldh8(Bh + bo + 8));
      sth8(&BsL[row * 72 + spart * 16], ldh8(Bl + bo));
      sth8(&BsL[row * 72 + spart * 16 + 8], ldh8(Bl + bo + 8));
    }
    __syncthreads();
#pragma unroll
    for (int ks = 0; ks < 2; ++ks) {
      const half8 a0h = ldh8(&AsH[(32 * wq + lrow) * 72 + lk8 + 32 * ks]);
      const half8 a1h = ldh8(&AsH[(32 * wq + 16 + lrow) * 72 + lk8 + 32 * ks]);
      const half8 a0l = ldh8(&AsL[(32 * wq + lrow) * 72 + lk8 + 32 * ks]);
      const half8 a1l = ldh8(&AsL[(32 * wq + 16 + lrow) * 72 + lk8 + 32 * ks]);
#pragma unroll
      for (int nt = 0; nt < 8; ++nt) {
        const half8 bh = ldh8(&BsH[(16 * nt + lrow) * 72 + lk8 + 32 * ks]);
        const half8 bl = ldh8(&BsL[(16 * nt + lrow) * 72 + lk8 + 32 * ks]);
        acc[0][nt] = mfma16(a0h, bh, acc[0][nt]);
        acc[0][nt] = mfma16(a0h, bl, acc[0][nt]);
        acc[0][nt] = mfma16(a0l, bh, acc[0][nt]);
        acc[1][nt] = mfma16(a1h, bh, acc[1][nt]);
        acc[1][nt] = mfma16(a1h, bl, acc[1][nt]);
        acc[1][nt] = mfma16(a1l, bh, acc[1][nt]);
      }
    }
  }
  __half* OH = Ch + (size_t)(n0 >> 7) * M * 128;
  __half* OL = Cl + (size_t)(n0 >> 7) * M * 128;
#pragma unroll
  for (int mt = 0; mt < 2; ++mt)
#pragma unroll
    for (int nt = 0; nt < 8; ++nt)
#pragma unroll
      for (int reg = 0; reg < 4; ++reg) {
        const int row = m0 + 32 * wq + 16 * mt + 4 * (lane >> 4) + reg;
        const float v = acc[mt][nt][reg];
        const __half hi = __float2half(v);
        OH[(size_t)row * 128 + 16 * nt + lrow] = hi;
        OL[(size_t)row * 128 + 16 * nt + lrow] =
            __float2half(v - __half2float(hi));
      }
}

// ------------- f16 MFMA NT GEMM: C[m][n] = sum_k A[m][k] * Bt[n][k] --------
template <int MODE>
__global__ __launch_bounds__(256, 4) void gemmh_k(const __half* __restrict__ A,
                                                  const __half* __restrict__ Bt,
                                                  void* __restrict__ Cout,
                                                  int M, int N, int KD) {
  __shared__ __half As[128 * 72];
  __shared__ __half Bs[128 * 72];
  const int tid = threadIdx.x;
  const int lane = tid & 63, wq = tid >> 6;
  const int lrow = lane & 15, lk8 = (lane >> 4) << 3;
  const int m0 = blockIdx.x * 128, n0 = blockIdx.y * 128;
  const int srow = tid >> 2, spart = tid & 3;

  f32x4 acc[2][8];
#pragma unroll
  for (int mt = 0; mt < 2; ++mt)
#pragma unroll
    for (int nt = 0; nt < 8; ++nt) acc[mt][nt] = (f32x4){0.f, 0.f, 0.f, 0.f};

  for (int kt = 0; kt < KD; kt += 64) {
    __syncthreads();
#pragma unroll
    for (int hh = 0; hh < 2; ++hh) {
      const int row = srow + hh * 64;
      const __half* pa = A + (size_t)(m0 + row) * KD + kt + spart * 16;
      const __half* pb = Bt + (size_t)(n0 + row) * KD + kt + spart * 16;
      sth8(&As[row * 72 + spart * 16], ldh8(pa));
      sth8(&As[row * 72 + spart * 16 + 8], ldh8(pa + 8));
      sth8(&Bs[row * 72 + spart * 16], ldh8(pb));
      sth8(&Bs[row * 72 + spart * 16 + 8], ldh8(pb + 8));
    }
    __syncthreads();
#pragma unroll
    for (int ks = 0; ks < 2; ++ks) {
      half8 a0 = ldh8(&As[(32 * wq + lrow) * 72 + lk8 + 32 * ks]);
      half8 a1 = ldh8(&As[(32 * wq + 16 + lrow) * 72 + lk8 + 32 * ks]);
#pragma unroll
      for (int nt = 0; nt < 8; ++nt) {
        half8 b = ldh8(&Bs[(16 * nt + lrow) * 72 + lk8 + 32 * ks]);
        acc[0][nt] = mfma16(a0, b, acc[0][nt]);
        acc[1][nt] = mfma16(a1, b, acc[1][nt]);
      }
    }
  }
  if (MODE == 0) {
    __half* O = reinterpret_cast<__half*>(Cout) + (size_t)(n0 >> 7) * M * 128;
#pragma unroll
    for (int mt = 0; mt < 2; ++mt)
#pragma unroll
      for (int nt = 0; nt < 8; ++nt)
#pragma unroll
        for (int reg = 0; reg < 4; ++reg) {
          const int row = m0 + 32 * wq + 16 * mt + 4 * (lane >> 4) + reg;
          O[(size_t)row * 128 + 16 * nt + lrow] = __float2half(acc[mt][nt][reg]);
        }
  } else {
    float* O = reinterpret_cast<float*>(Cout);
#pragma unroll
    for (int mt = 0; mt < 2; ++mt)
#pragma unroll
      for (int nt = 0; nt < 8; ++nt)
#pragma unroll
        for (int reg = 0; reg < 4; ++reg) {
          const int row = m0 + 32 * wq + 16 * mt + 4 * (lane >> 4) + reg;
          O[(size_t)row * N + n0 + 16 * nt + lrow] = acc[mt][nt][reg];
        }
  }
}

// ---------- split-f16 MFMA dot + argmin: z = argmin_s ||k - c_s||^2 --------
__global__ __launch_bounds__(256, 2) void argmin3_k(
    const __half* __restrict__ kbh, const __half* __restrict__ kbl,
    const __half* __restrict__ cbh, const __half* __restrict__ cbl,
    const float* __restrict__ cb2v, int* __restrict__ zb) {
  __shared__ __half BsH[64 * 136];
  __shared__ __half BsL[64 * 136];
  const int tid = threadIdx.x;
  const int lane = tid & 63, wq = tid >> 6;
  const int lrow = lane & 15, lk8 = (lane >> 4) << 3;
  const int m0 = blockIdx.x * 128;
  const int h = blockIdx.y;
  const int srow = tid >> 2, spart = tid & 3;
  const size_t kbase = (size_t)h * (Bn * Tn);

  half8 ah[2][4], al[2][4];
#pragma unroll
  for (int mt = 0; mt < 2; ++mt)
#pragma unroll
    for (int ks = 0; ks < 4; ++ks) {
      const size_t off =
          (kbase + m0 + 32 * wq + 16 * mt + lrow) * 128 + lk8 + 32 * ks;
      ah[mt][ks] = ldh8(kbh + off);
      al[mt][ks] = ldh8(kbl + off);
    }

  float best[2][4];
  int bidx[2][4];
#pragma unroll
  for (int mt = 0; mt < 2; ++mt)
#pragma unroll
    for (int reg = 0; reg < 4; ++reg) {
      best[mt][reg] = 3.0e38f;
      bidx[mt][reg] = 0;
    }

  for (int s0 = 0; s0 < Sn; s0 += 64) {
    __syncthreads();
    {
      const size_t bo = ((size_t)h * Sn + s0 + srow) * 128 + spart * 32;
      sth8(&BsH[srow * 136 + spart * 32], ldh8(cbh + bo));
      sth8(&BsH[srow * 136 + spart * 32 + 8], ldh8(cbh + bo + 8));
      sth8(&BsH[srow * 136 + spart * 32 + 16], ldh8(cbh + bo + 16));
      sth8(&BsH[srow * 136 + spart * 32 + 24], ldh8(cbh + bo + 24));
      sth8(&BsL[srow * 136 + spart * 32], ldh8(cbl + bo));
      sth8(&BsL[srow * 136 + spart * 32 + 8], ldh8(cbl + bo + 8));
      sth8(&BsL[srow * 136 + spart * 32 + 16], ldh8(cbl + bo + 16));
      sth8(&BsL[srow * 136 + spart * 32 + 24], ldh8(cbl + bo + 24));
    }
    __syncthreads();
    f32x4 acc[2][4];
#pragma unroll
    for (int mt = 0; mt < 2; ++mt)
#pragma unroll
      for (int nt = 0; nt < 4; ++nt) acc[mt][nt] = (f32x4){0.f, 0.f, 0.f, 0.f};
#pragma unroll
    for (int ks = 0; ks < 4; ++ks)
#pragma unroll
      for (int nt = 0; nt < 4; ++nt) {
        const half8 bh = ldh8(&BsH[(16 * nt + lrow) * 136 + lk8 + 32 * ks]);
        const half8 bl = ldh8(&BsL[(16 * nt + lrow) * 136 + lk8 + 32 * ks]);
        acc[0][nt] = mfma16(ah[0][ks], bh, acc[0][nt]);
        acc[0][nt] = mfma16(ah[0][ks], bl, acc[0][nt]);
        acc[0][nt] = mfma16(al[0][ks], bh, acc[0][nt]);
        acc[1][nt] = mfma16(ah[1][ks], bh, acc[1][nt]);
        acc[1][nt] = mfma16(ah[1][ks], bl, acc[1][nt]);
        acc[1][nt] = mfma16(al[1][ks], bh, acc[1][nt]);
      }
#pragma unroll
    for (int mt = 0; mt < 2; ++mt)
#pragma unroll
      for (int nt = 0; nt < 4; ++nt) {
        const int s = s0 + 16 * nt + lrow;
        const float c2 = cb2v[h * Sn + s];
#pragma unroll
        for (int reg = 0; reg < 4; ++reg) {
          const float d2 = c2 - 2.0f * acc[mt][nt][reg];
          if (d2 < best[mt][reg]) {
            best[mt][reg] = d2;
            bidx[mt][reg] = s;
          }
        }
      }
  }
#pragma unroll
  for (int xb = 1; xb <= 8; xb <<= 1) {
#pragma unroll
    for (int mt = 0; mt < 2; ++mt)
#pragma unroll
      for (int reg = 0; reg < 4; ++reg) {
        const float ob = __shfl_xor(best[mt][reg], xb);
        const int oi = __shfl_xor(bidx[mt][reg], xb);
        if (ob < best[mt][reg] ||
            (ob == best[mt][reg] && oi < bidx[mt][reg])) {
          best[mt][reg] = ob;
          bidx[mt][reg] = oi;
        }
      }
  }
  if (lrow == 0) {
#pragma unroll
    for (int mt = 0; mt < 2; ++mt)
#pragma unroll
      for (int reg = 0; reg < 4; ++reg) {
        const int row = m0 + 32 * wq + 16 * mt + 4 * (lane >> 4) + reg;
        zb[kbase + row] = bidx[mt][reg];
      }
  }
}

// ------- scan: cumulative cluster stats -> udl (f16) + bias, LDS-local -----
__global__ __launch_bounds__(256) void scan_k(const int* __restrict__ zb,
                                              const __half* __restrict__ vb,
                                              __half* __restrict__ udl,
                                              float* __restrict__ biasv) {
  __shared__ float acc[128][128];
  __shared__ float cnt[128];
  const int tid = threadIdx.x;
  const int sc = blockIdx.x, b = blockIdx.y, h = blockIdx.z;
  const int s0 = sc * 128;
  for (int i = tid; i < 128 * 128; i += 256) acc[i >> 7][i & 127] = 0.f;
  if (tid < 128) cnt[tid] = 0.f;
  __syncthreads();
  const size_t tokH = (size_t)h * (Bn * Tn) + (size_t)b * Tn;
  const int dd = tid & 127, halfh = tid >> 7;
  for (int r = 0; r < Rn; ++r) {
    for (int i = tid; i < 128 * 128; i += 256) {
      const int srow = i >> 7, d = i & 127;
      const float c = cnt[srow];
      const float v = acc[srow][d] / fmaxf(c, 1.f);
      udl[((((size_t)h * Bn + b) * Rn + r) * Sn + s0 + srow) * Vn + d] =
          __float2half(v);
    }
    if (tid < 128) {
      const float c = cnt[tid];
      biasv[(((size_t)h * Bn + b) * Rn + r) * Sn + s0 + tid] =
          (c > 0.f) ? logf(c) : -NEGV;
    }
    __syncthreads();
    if (r >= 1 && r < 7) {
      const int tb = (r - 1) * Cn;
#pragma unroll 4
      for (int u = 0; u < 128; ++u) {
        const int tok = tb + u * 2 + halfh;
        const int s = zb[tokH + tok];
        if (s >= s0 && s < s0 + 128) {
          const float v = __half2float(vb[(tokH + tok) * Vn + dd]);
          atomicAdd(&acc[s - s0][dd], v);
          if (dd == 0) atomicAdd(&cnt[s - s0], 1.0f);
        }
      }
    }
    __syncthreads();
  }
}

// ---------------- MFMA fused attention ----------------
__global__ __launch_bounds__(256, 2) void attn3_k(
    const __half* __restrict__ qbh, const __half* __restrict__ vbh,
    const __half* __restrict__ udl, const __half* __restrict__ cbh,
    const __half* __restrict__ xlrh, const float* __restrict__ biasv,
    const float* __restrict__ duv, const int* __restrict__ zb,
    const float* __restrict__ xlu, __half* __restrict__ aout) {
  __shared__ __half quS[64 * 136];
  __shared__ __half KXS[64 * 136];
  __shared__ __half VtS[128 * 72];
  __shared__ __half PBD[64 * 136];
  __shared__ float duvS[128];
  __shared__ float biasS[64];

  const int tid = threadIdx.x;
  const int lane = tid & 63, wq = tid >> 6;
  const int lrow = lane & 15, lk8 = (lane >> 4) << 3;
  const int qt = blockIdx.x;
  const int b = blockIdx.y >> 3, r = blockIdx.y & 7;
  const int h = blockIdx.z;
  const int c0 = qt * 64;
  const int tBlk = r * Cn + c0;
  const size_t tokH = (size_t)h * (Bn * Tn) + (size_t)b * Tn;
  const size_t sBase = (((size_t)h * Bn + b) * Rn + r) * Sn;
  const int srow = tid >> 2, spart = tid & 3;
  const int kp = tid >> 3, p8 = tid & 7;

  {
    const __half* src = qbh + (tokH + tBlk + srow) * Kn + spart * 32;
    const float* up = xlu + h * Kn + spart * 32;
    alignas(16) __half tmp[32];
#pragma unroll
    for (int e = 0; e < 32; ++e)
      tmp[e] = __float2half(__half2float(src[e]) + up[e]);
#pragma unroll
    for (int g2 = 0; g2 < 4; ++g2)
      sth8(&quS[srow * 136 + spart * 32 + g2 * 8],
           *reinterpret_cast<half8*>(&tmp[g2 * 8]));
  }

  float mR[4], lR[4];
  f32x4 Oacc[8];
#pragma unroll
  for (int i = 0; i < 4; ++i) {
    mR[i] = -NEGV;
    lR[i] = 0.f;
  }
#pragma unroll
  for (int nt = 0; nt < 8; ++nt) Oacc[nt] = (f32x4){0.f, 0.f, 0.f, 0.f};

  half8 a[4];
  bool aLoaded = false;

  for (int ch = 0; ch < 16; ++ch) {
    const bool isC = (ch < 8);
    const int s0 = ch * 64;
    const int w0 = (ch - 8) * 64;
    const int jbase = w0 + 192 - c0;
    __syncthreads();
    if (isC) {
      const __half* ks = cbh + ((size_t)h * Sn + s0 + srow) * Kn + spart * 32;
      sth8(&KXS[srow * 136 + spart * 32], ldh8(ks));
      sth8(&KXS[srow * 136 + spart * 32 + 8], ldh8(ks + 8));
      sth8(&KXS[srow * 136 + spart * 32 + 16], ldh8(ks + 16));
      sth8(&KXS[srow * 136 + spart * 32 + 24], ldh8(ks + 24));
      const __half* u0 = udl + (sBase + s0 + 2 * kp) * Vn + p8 * 16;
      const __half* u1 = u0 + Vn;
#pragma unroll
      for (int e = 0; e < 16; ++e) {
        const int d = p8 * 16 + e;
        const int gidx = ((2 * kp) >> 3) ^ ((d >> 4) & 7);
        *reinterpret_cast<__half2*>(
            &VtS[d * 72 + gidx * 8 + ((2 * kp) & 7)]) =
            __halves2half2(u0[e], u1[e]);
      }
      if (tid < 64) biasS[tid] = biasv[sBase + s0 + tid];
    } else {
      int tk = (r - 1) * Cn + w0 + srow;
      if (tk < 0) tk = 0;
      const int code = zb[tokH + tk];
      const __half* ks = cbh + ((size_t)h * Sn + code) * Kn + spart * 32;
      sth8(&KXS[srow * 136 + spart * 32], ldh8(ks));
      sth8(&KXS[srow * 136 + spart * 32 + 8], ldh8(ks + 8));
      sth8(&KXS[srow * 136 + spart * 32 + 16], ldh8(ks + 16));
      sth8(&KXS[srow * 136 + spart * 32 + 24], ldh8(ks + 24));
      const int tk0 = (r - 1) * Cn + w0 + 2 * kp;
      const int tka = tk0 < 0 ? 0 : tk0;
      const int tkb = tk0 + 1 < 0 ? 0 : tk0 + 1;
      const __half* v0 = vbh + (tokH + tka) * Kn + p8 * 16;
      const __half* v1 = vbh + (tokH + tkb) * Kn + p8 * 16;
#pragma unroll
      for (int e = 0; e < 16; ++e) {
        const int d = p8 * 16 + e;
        const int gidx = ((2 * kp) >> 3) ^ ((d >> 4) & 7);
        *reinterpret_cast<__half2*>(
            &VtS[d * 72 + gidx * 8 + ((2 * kp) & 7)]) =
            __halves2half2(v0[e], v1[e]);
      }
    }
    __syncthreads();
    if (!aLoaded) {
#pragma unroll
      for (int ks = 0; ks < 4; ++ks)
        a[ks] = ldh8(&quS[(16 * wq + lrow) * 136 + lk8 + 32 * ks]);
      aLoaded = true;
    }
    f32x4 acc[4];
#pragma unroll
    for (int nt = 0; nt < 4; ++nt) acc[nt] = (f32x4){0.f, 0.f, 0.f, 0.f};
#pragma unroll
    for (int ks = 0; ks < 4; ++ks)
#pragma unroll
      for (int nt = 0; nt < 4; ++nt)
        acc[nt] = mfma16(
            a[ks], ldh8(&KXS[(16 * nt + lrow) * 136 + lk8 + 32 * ks]),
            acc[nt]);

    float lg[4][4];
    if (isC) {
#pragma unroll
      for (int nt = 0; nt < 4; ++nt) {
        const float bv = biasS[lrow + 16 * nt];
#pragma unroll
        for (int reg = 0; reg < 4; ++reg)
          lg[nt][reg] = acc[nt][reg] * INV_TAU + bv;
      }
    } else {
#pragma unroll
      for (int hh = 0; hh < 2; ++hh) {
        __syncthreads();
        {
          int j = jbase + hh * 64 + srow;
          j = j < 0 ? 0 : (j > Wn - 1 ? Wn - 1 : j);
          const __half* xs = xlrh + ((size_t)h * Wn + j) * Kn + spart * 32;
          sth8(&KXS[srow * 136 + spart * 32], ldh8(xs));
          sth8(&KXS[srow * 136 + spart * 32 + 8], ldh8(xs + 8));
          sth8(&KXS[srow * 136 + spart * 32 + 16], ldh8(xs + 16));
          sth8(&KXS[srow * 136 + spart * 32 + 24], ldh8(xs + 24));
          if (hh == 0 && tid < 128) {
            int jx = jbase + tid;
            jx = jx < 0 ? 0 : (jx > Wn - 1 ? Wn - 1 : jx);
            duvS[tid] = duv[h * Wn + jx];
          }
        }
        __syncthreads();
        f32x4 bdh[4];
#pragma unroll
        for (int nt = 0; nt < 4; ++nt) bdh[nt] = (f32x4){0.f, 0.f, 0.f, 0.f};
#pragma unroll
        for (int ks = 0; ks < 4; ++ks)
#pragma unroll
          for (int nt = 0; nt < 4; ++nt)
            bdh[nt] = mfma16(
                a[ks], ldh8(&KXS[(16 * nt + lrow) * 136 + lk8 + 32 * ks]),
                bdh[nt]);
#pragma unroll
        for (int nt = 0; nt < 4; ++nt) {
          const int col = hh * 64 + 16 * nt + lrow;
          const float dv = duvS[col];
#pragma unroll
          for (int reg = 0; reg < 4; ++reg) {
            const int row64 = 16 * wq + 4 * (lane >> 4) + reg;
            PBD[row64 * 136 + col] = __float2half(bdh[nt][reg] + dv);
          }
        }
      }
      __syncthreads();
#pragma unroll
      for (int nt = 0; nt < 4; ++nt) {
        const int key = lrow + 16 * nt;
        const int w = w0 + key;
#pragma unroll
        for (int reg = 0; reg < 4; ++reg) {
          const int row64 = 16 * wq + 4 * (lane >> 4) + reg;
          const bool valid = (w <= c0 + row64 + Cn) && !(r == 0 && w < Cn);
          const float bdv = __half2float(PBD[row64 * 136 + key + 63 - row64]);
          lg[nt][reg] = valid ? (acc[nt][reg] + bdv) * INV_TAU : -NEGV;
        }
      }
      __syncthreads();
    }
    float p[4][4], scl[4];
#pragma unroll
    for (int reg = 0; reg < 4; ++reg) {
      float rm = fmaxf(fmaxf(lg[0][reg], lg[1][reg]),
                       fmaxf(lg[2][reg], lg[3][reg]));
      rm = fmaxf(rm, __shfl_xor(rm, 1));
      rm = fmaxf(rm, __shfl_xor(rm, 2));
      rm = fmaxf(rm, __shfl_xor(rm, 4));
      rm = fmaxf(rm, __shfl_xor(rm, 8));
      const float mn = fmaxf(mR[reg], rm);
      scl[reg] = __expf(mR[reg] - mn);
      float rs = 0.f;
#pragma unroll
      for (int nt = 0; nt < 4; ++nt) {
        p[nt][reg] = __expf(lg[nt][reg] - mn);
        rs += p[nt][reg];
      }
      rs += __shfl_xor(rs, 1);
      rs += __shfl_xor(rs, 2);
      rs += __shfl_xor(rs, 4);
      rs += __shfl_xor(rs, 8);
      lR[reg] = lR[reg] * scl[reg] + rs;
      mR[reg] = mn;
    }
#pragma unroll
    for (int nt = 0; nt < 8; ++nt)
#pragma unroll
      for (int reg = 0; reg < 4; ++reg) Oacc[nt][reg] *= scl[reg];
#pragma unroll
    for (int nt = 0; nt < 4; ++nt)
#pragma unroll
      for (int reg = 0; reg < 4; ++reg) {
        const int row64 = 16 * wq + 4 * (lane >> 4) + reg;
        PBD[row64 * 136 + lrow + 16 * nt] = __float2half(p[nt][reg]);
      }
    __syncthreads();
#pragma unroll
    for (int ks = 0; ks < 2; ++ks) {
      half8 pa = ldh8(&PBD[(16 * wq + lrow) * 136 + lk8 + 32 * ks]);
#pragma unroll
      for (int nt = 0; nt < 8; ++nt) {
        const int gidx = (((lk8 + 32 * ks) >> 3) ^ nt);
        half8 vb = ldh8(&VtS[(16 * nt + lrow) * 72 + gidx * 8]);
        Oacc[nt] = mfma16(pa, vb, Oacc[nt]);
      }
    }
  }
  float inv[4];
#pragma unroll
  for (int reg = 0; reg < 4; ++reg) inv[reg] = 1.0f / lR[reg];
#pragma unroll
  for (int nt = 0; nt < 8; ++nt)
#pragma unroll
    for (int reg = 0; reg < 4; ++reg) {
      const int row64 = 16 * wq + 4 * (lane >> 4) + reg;
      aout[((size_t)b * Tn + tBlk + row64) * (Hn * Vn) + h * Vn + 16 * nt +
           lrow] = __float2half(Oacc[nt][reg] * inv[reg]);
    }
}

// ---------------- launcher ----------------
extern "C" void kernel_launch(void* const* d_in, const int* in_sizes, int n_in,
                              void* d_out, int out_size, void* d_ws,
                              size_t ws_size, hipStream_t stream) {
  (void)in_sizes;
  (void)n_in;
  (void)out_size;
  const float* x = (const float*)d_in[0];
  const float* g_ln = (const float*)d_in[1];
  const float* Wq = (const float*)d_in[2];
  const float* Wk = (const float*)d_in[3];
  const float* Wv = (const float*)d_in[4];
  const float* cb = (const float*)d_in[5];
  const float* xl_r = (const float*)d_in[6];
  const float* xl_u = (const float*)d_in[7];
  const float* xl_v = (const float*)d_in[8];
  const float* Wo = (const float*)d_in[9];
  float* out = (float*)d_out;

  float* W = (float*)d_ws;
  size_t o = 0;
  __half* xth = (__half*)(W + o);         // aliased later by aout (exact fit)
  __half* aout = xth;
  o += (size_t)Bn * Tn * Dn / 2;          // 4,194,304
  __half* xtl = (__half*)(W + o);
  o += (size_t)Bn * Tn * Dn / 2;          // 4,194,304
  __half* kbh = (__half*)(W + o);         // k hi/lo; aliased later by udl
  __half* udlh = kbh;
  o += (size_t)Hn * Bn * Tn * Kn / 2;     // 4,194,304
  __half* kbl = (__half*)(W + o);
  o += (size_t)Hn * Bn * Tn * Kn / 2;     // 4,194,304
  __half* qbh = (__half*)(W + o);
  o += (size_t)Hn * Bn * Tn * Kn / 2;     // 2,097,152
  __half* vbh = (__half*)(W + o);
  o += (size_t)Hn * Bn * Tn * Vn / 2;     // 2,097,152
  __half* cbh = (__half*)(W + o);
  o += (size_t)Hn * Sn * Kn / 2;          // 131,072
  __half* cbl = (__half*)(W + o);
  o += (size_t)Hn * Sn * Kn / 2;          // 131,072
  __half* xlrh = (__half*)(W + o);
  o += (size_t)Hn * Wn * Kn / 2;          // 131,072
  int* zb = (int*)(W + o);
  o += (size_t)Hn * Bn * Tn;              // 65,536
  float* biasb = W + o;
  o += (size_t)Hn * Bn * Rn * Sn;         // 131,072
  float* duvb = W + o;
  o += (size_t)Hn * Wn;                   // 4,096
  float* cb2b = W + o;
  o += (size_t)Hn * Sn;                   // 4,096
  __half* wkth = (__half*)(W + o);
  o += (size_t)Dn * Dn / 2;               // 524,288
  __half* wktl = (__half*)(W + o);
  o += (size_t)Dn * Dn / 2;
  __half* wqt = (__half*)(W + o);
  o += (size_t)Dn * Dn / 2;
  __half* wvt = (__half*)(W + o);
  o += (size_t)Dn * Dn / 2;
  __half* wot = (__half*)(W + o);
  o += (size_t)Dn * Dn / 2;

  if (ws_size < o * sizeof(float)) return;  // bail visibly if ws too small

  rms3_k<<<Bn * Tn, 256, 0, stream>>>(x, g_ln, xth, xtl);
  transcvt2_k<<<dim3(32, 32), 256, 0, stream>>>(Wk, wkth, wktl);
  transcvt_k<<<dim3(32, 32), 256, 0, stream>>>(Wq, wqt);
  transcvt_k<<<dim3(32, 32), 256, 0, stream>>>(Wv, wvt);
  transcvt_k<<<dim3(32, 32), 256, 0, stream>>>(Wo, wot);
  cb2_k<<<Hn * Sn / 256, 256, 0, stream>>>(cb, cb2b);
  cvt2_k<<<2 * Hn * Sn * Kn / 256, 256, 0, stream>>>(cb, xl_r, cbh, cbl, xlrh);
  duv_k<<<Hn, 256, 0, stream>>>(xl_r, xl_u, xl_v, duvb);

  kproj_k<<<dim3(64, 8), 256, 0, stream>>>(xth, xtl, wkth, wktl, kbh, kbl,
                                           8192, 1024);
  gemmh_k<0><<<dim3(64, 8), 256, 0, stream>>>(xth, wqt, qbh, 8192, 1024, 1024);
  gemmh_k<0><<<dim3(64, 8), 256, 0, stream>>>(xth, wvt, vbh, 8192, 1024, 1024);

  argmin3_k<<<dim3(Bn * Tn / 128, Hn), 256, 0, stream>>>(kbh, kbl, cbh, cbl,
                                                         cb2b, zb);
  scan_k<<<dim3(4, Bn, Hn), 256, 0, stream>>>(zb, vbh, udlh, biasb);

  attn3_k<<<dim3(4, Bn * Rn, Hn), 256, 0, stream>>>(
      qbh, vbh, udlh, cbh, xlrh, biasb, duvb, zb, xl_u, aout);

  gemmh_k<1><<<dim3(64, 8), 256, 0, stream>>>(aout, wot, out, 8192, 1024,
                                              1024);
}

// Round 6
// 434.674 us; speedup vs baseline: 13.8081x; 1.2997x over previous
//
#include <hip/hip_runtime.h>
#include <hip/hip_fp16.h>

typedef _Float16 half8 __attribute__((ext_vector_type(8)));
typedef float f32x4 __attribute__((ext_vector_type(4)));

constexpr int Bn = 4, Tn = 2048, Dn = 1024, Hn = 8, Kn = 128, Vn = 128;
constexpr int Sn = 512, Cn = 256, Rn = 8, Wn = 512;
constexpr float NEGV = 1.0e30f;
constexpr float INV_TAU = 0.08838834764831845f;  // 1/sqrt(128)

__device__ __forceinline__ half8 ldh8(const __half* p) {
  return *reinterpret_cast<const half8*>(p);
}
__device__ __forceinline__ void sth8(__half* p, half8 v) {
  *reinterpret_cast<half8*>(p) = v;
}
__device__ __forceinline__ f32x4 mfma16(half8 a, half8 b, f32x4 c) {
  return __builtin_amdgcn_mfma_f32_16x16x32_f16(a, b, c, 0, 0, 0);
}

// ---------------- RMSNorm -> split f16 (hi + residual) ----------------
__global__ __launch_bounds__(256) void rms3_k(const float* __restrict__ x,
                                              const float* __restrict__ g,
                                              __half* __restrict__ xth,
                                              __half* __restrict__ xtl) {
  const int row = blockIdx.x;
  const int tid = threadIdx.x;
  const float4 v = reinterpret_cast<const float4*>(x + (size_t)row * Dn)[tid];
  float ss = v.x * v.x + v.y * v.y + v.z * v.z + v.w * v.w;
#pragma unroll
  for (int o = 32; o > 0; o >>= 1) ss += __shfl_xor(ss, o);
  __shared__ float red[4];
  if ((tid & 63) == 0) red[tid >> 6] = ss;
  __syncthreads();
  const float tot = red[0] + red[1] + red[2] + red[3];
  const float sc = rsqrtf(tot * (1.0f / Dn) + 1e-6f);
  const float4 gv = reinterpret_cast<const float4*>(g)[tid];
  float vv[4] = {v.x * sc * gv.x, v.y * sc * gv.y, v.z * sc * gv.z,
                 v.w * sc * gv.w};
  __half hi[4], lo[4];
#pragma unroll
  for (int e = 0; e < 4; ++e) {
    hi[e] = __float2half(vv[e]);
    lo[e] = __float2half(vv[e] - __half2float(hi[e]));
  }
  __half2* oph = reinterpret_cast<__half2*>(xth + (size_t)row * Dn + tid * 4);
  __half2* opl = reinterpret_cast<__half2*>(xtl + (size_t)row * Dn + tid * 4);
  oph[0] = __halves2half2(hi[0], hi[1]);
  oph[1] = __halves2half2(hi[2], hi[3]);
  opl[0] = __halves2half2(lo[0], lo[1]);
  opl[1] = __halves2half2(lo[2], lo[3]);
}

// ---------------- transpose + f32->f16: dst[n][d] = src[d][n] ----------------
__global__ __launch_bounds__(256) void transcvt_k(const float* __restrict__ src,
                                                  __half* __restrict__ dst) {
  __shared__ float ts[32][33];
  const int bx = blockIdx.x, by = blockIdx.y;
  const int j = threadIdx.x & 31, i0 = threadIdx.x >> 5;
#pragma unroll
  for (int rr = 0; rr < 4; ++rr) {
    const int row = i0 + rr * 8;
    ts[row][j] = src[(size_t)(by * 32 + row) * 1024 + bx * 32 + j];
  }
  __syncthreads();
#pragma unroll
  for (int rr = 0; rr < 4; ++rr) {
    const int row = i0 + rr * 8;
    dst[(size_t)(bx * 32 + row) * 1024 + by * 32 + j] = __float2half(ts[j][row]);
  }
}

// ------------- transpose + split f16 (hi + residual), for Wk ---------------
__global__ __launch_bounds__(256) void transcvt2_k(
    const float* __restrict__ src, __half* __restrict__ dh,
    __half* __restrict__ dl) {
  __shared__ float ts[32][33];
  const int bx = blockIdx.x, by = blockIdx.y;
  const int j = threadIdx.x & 31, i0 = threadIdx.x >> 5;
#pragma unroll
  for (int rr = 0; rr < 4; ++rr) {
    const int row = i0 + rr * 8;
    ts[row][j] = src[(size_t)(by * 32 + row) * 1024 + bx * 32 + j];
  }
  __syncthreads();
#pragma unroll
  for (int rr = 0; rr < 4; ++rr) {
    const int row = i0 + rr * 8;
    const float v = ts[j][row];
    const __half hi = __float2half(v);
    dh[(size_t)(bx * 32 + row) * 1024 + by * 32 + j] = hi;
    dl[(size_t)(bx * 32 + row) * 1024 + by * 32 + j] =
        __float2half(v - __half2float(hi));
  }
}

// ---------------- codebook squared norms ----------------
__global__ __launch_bounds__(256) void cb2_k(const float* __restrict__ cb,
                                             float* __restrict__ cb2v) {
  const int idx = blockIdx.x * 256 + threadIdx.x;  // < H*S
  const float4* rp = reinterpret_cast<const float4*>(cb + (size_t)idx * Kn);
  float ss = 0.f;
#pragma unroll 8
  for (int i = 0; i < Kn / 4; ++i) {
    const float4 v = rp[i];
    ss += v.x * v.x + v.y * v.y + v.z * v.z + v.w * v.w;
  }
  cb2v[idx] = ss;
}

// -------- f32 -> f16 conversion: cb (hi+lo) and xl_r (hi only) --------
__global__ __launch_bounds__(256) void cvt2_k(const float* __restrict__ cb,
                                              const float* __restrict__ xlr,
                                              __half* __restrict__ cbh,
                                              __half* __restrict__ cbl,
                                              __half* __restrict__ xlrh) {
  const int i = blockIdx.x * 256 + threadIdx.x;
  constexpr int NE = Hn * Sn * Kn;  // 524288
  if (i < NE) {
    const float v = cb[i];
    const __half hi = __float2half(v);
    cbh[i] = hi;
    cbl[i] = __float2half(v - __half2float(hi));
  } else {
    xlrh[i - NE] = __float2half(xlr[i - NE]);
  }
}

// ---------------- duv[h][j] = (xl_v - xl_u) . xl_r[h][j] ----------------
__global__ __launch_bounds__(256) void duv_k(const float* __restrict__ xlr,
                                             const float* __restrict__ xlu,
                                             const float* __restrict__ xlv,
                                             float* __restrict__ duv) {
  const int h = blockIdx.x;
  const float* up = xlu + h * Kn;
  const float* vp = xlv + h * Kn;
  for (int j = threadIdx.x; j < Wn; j += 256) {
    const float* rp = xlr + ((size_t)h * Wn + j) * Kn;
    float s = 0.f;
#pragma unroll 8
    for (int d = 0; d < Kn; ++d) s = fmaf(vp[d] - up[d], rp[d], s);
    duv[h * Wn + j] = s;
  }
}

// ------- split-f16 MFMA k-projection: k = (xh+xl).(wh+wl), 3 terms ---------
__global__ __launch_bounds__(256, 2) void kproj_k(
    const __half* __restrict__ Ah, const __half* __restrict__ Al,
    const __half* __restrict__ Bh, const __half* __restrict__ Bl,
    __half* __restrict__ Ch, __half* __restrict__ Cl, int M, int KD) {
  __shared__ __half AsH[128 * 72];
  __shared__ __half AsL[128 * 72];
  __shared__ __half BsH[128 * 72];
  __shared__ __half BsL[128 * 72];
  const int tid = threadIdx.x;
  const int lane = tid & 63, wq = tid >> 6;
  const int lrow = lane & 15, lk8 = (lane >> 4) << 3;
  const int m0 = blockIdx.x * 128, n0 = blockIdx.y * 128;
  const int srow = tid >> 2, spart = tid & 3;

  f32x4 acc[2][8];
#pragma unroll
  for (int mt = 0; mt < 2; ++mt)
#pragma unroll
    for (int nt = 0; nt < 8; ++nt) acc[mt][nt] = (f32x4){0.f, 0.f, 0.f, 0.f};

  for (int kt = 0; kt < KD; kt += 64) {
    __syncthreads();
#pragma unroll
    for (int hh = 0; hh < 2; ++hh) {
      const int row = srow + hh * 64;
      const size_t ao = (size_t)(m0 + row) * KD + kt + spart * 16;
      const size_t bo = (size_t)(n0 + row) * KD + kt + spart * 16;
      sth8(&AsH[row * 72 + spart * 16], ldh8(Ah + ao));
      sth8(&AsH[row * 72 + spart * 16 + 8], ldh8(Ah + ao + 8));
      sth8(&AsL[row * 72 + spart * 16], ldh8(Al + ao));
      sth8(&AsL[row * 72 + spart * 16 + 8], ldh8(Al + ao + 8));
      sth8(&BsH[row * 72 + spart * 16], ldh8(Bh + bo));
      sth8(&BsH[row * 72 + spart * 16 + 8], ldh8(Bh + bo + 8));
      sth8(&BsL[row * 72 + spart * 16], ldh8(Bl + bo));
      sth8(&BsL[row * 72 + spart * 16 + 8], ldh8(Bl + bo + 8));
    }
    __syncthreads();
#pragma unroll
    for (int ks = 0; ks < 2; ++ks) {
      const half8 a0h = ldh8(&AsH[(32 * wq + lrow) * 72 + lk8 + 32 * ks]);
      const half8 a1h = ldh8(&AsH[(32 * wq + 16 + lrow) * 72 + lk8 + 32 * ks]);
      const half8 a0l = ldh8(&AsL[(32 * wq + lrow) * 72 + lk8 + 32 * ks]);
      const half8 a1l = ldh8(&AsL[(32 * wq + 16 + lrow) * 72 + lk8 + 32 * ks]);
#pragma unroll
      for (int nt = 0; nt < 8; ++nt) {
        const half8 bh = ldh8(&BsH[(16 * nt + lrow) * 72 + lk8 + 32 * ks]);
        const half8 bl = ldh8(&BsL[(16 * nt + lrow) * 72 + lk8 + 32 * ks]);
        acc[0][nt] = mfma16(a0h, bh, acc[0][nt]);
        acc[0][nt] = mfma16(a0h, bl, acc[0][nt]);
        acc[0][nt] = mfma16(a0l, bh, acc[0][nt]);
        acc[1][nt] = mfma16(a1h, bh, acc[1][nt]);
        acc[1][nt] = mfma16(a1h, bl, acc[1][nt]);
        acc[1][nt] = mfma16(a1l, bh, acc[1][nt]);
      }
    }
  }
  __half* OH = Ch + (size_t)(n0 >> 7) * M * 128;
  __half* OL = Cl + (size_t)(n0 >> 7) * M * 128;
#pragma unroll
  for (int mt = 0; mt < 2; ++mt)
#pragma unroll
    for (int nt = 0; nt < 8; ++nt)
#pragma unroll
      for (int reg = 0; reg < 4; ++reg) {
        const int row = m0 + 32 * wq + 16 * mt + 4 * (lane >> 4) + reg;
        const float v = acc[mt][nt][reg];
        const __half hi = __float2half(v);
        OH[(size_t)row * 128 + 16 * nt + lrow] = hi;
        OL[(size_t)row * 128 + 16 * nt + lrow] =
            __float2half(v - __half2float(hi));
      }
}

// ------------- f16 MFMA NT GEMM: C[m][n] = sum_k A[m][k] * Bt[n][k] --------
template <int MODE>
__global__ __launch_bounds__(256, 4) void gemmh_k(const __half* __restrict__ A,
                                                  const __half* __restrict__ Bt,
                                                  void* __restrict__ Cout,
                                                  int M, int N, int KD) {
  __shared__ __half As[128 * 72];
  __shared__ __half Bs[128 * 72];
  const int tid = threadIdx.x;
  const int lane = tid & 63, wq = tid >> 6;
  const int lrow = lane & 15, lk8 = (lane >> 4) << 3;
  const int m0 = blockIdx.x * 128, n0 = blockIdx.y * 128;
  const int srow = tid >> 2, spart = tid & 3;

  f32x4 acc[2][8];
#pragma unroll
  for (int mt = 0; mt < 2; ++mt)
#pragma unroll
    for (int nt = 0; nt < 8; ++nt) acc[mt][nt] = (f32x4){0.f, 0.f, 0.f, 0.f};

  for (int kt = 0; kt < KD; kt += 64) {
    __syncthreads();
#pragma unroll
    for (int hh = 0; hh < 2; ++hh) {
      const int row = srow + hh * 64;
      const __half* pa = A + (size_t)(m0 + row) * KD + kt + spart * 16;
      const __half* pb = Bt + (size_t)(n0 + row) * KD + kt + spart * 16;
      sth8(&As[row * 72 + spart * 16], ldh8(pa));
      sth8(&As[row * 72 + spart * 16 + 8], ldh8(pa + 8));
      sth8(&Bs[row * 72 + spart * 16], ldh8(pb));
      sth8(&Bs[row * 72 + spart * 16 + 8], ldh8(pb + 8));
    }
    __syncthreads();
#pragma unroll
    for (int ks = 0; ks < 2; ++ks) {
      half8 a0 = ldh8(&As[(32 * wq + lrow) * 72 + lk8 + 32 * ks]);
      half8 a1 = ldh8(&As[(32 * wq + 16 + lrow) * 72 + lk8 + 32 * ks]);
#pragma unroll
      for (int nt = 0; nt < 8; ++nt) {
        half8 b = ldh8(&Bs[(16 * nt + lrow) * 72 + lk8 + 32 * ks]);
        acc[0][nt] = mfma16(a0, b, acc[0][nt]);
        acc[1][nt] = mfma16(a1, b, acc[1][nt]);
      }
    }
  }
  if (MODE == 0) {
    __half* O = reinterpret_cast<__half*>(Cout) + (size_t)(n0 >> 7) * M * 128;
#pragma unroll
    for (int mt = 0; mt < 2; ++mt)
#pragma unroll
      for (int nt = 0; nt < 8; ++nt)
#pragma unroll
        for (int reg = 0; reg < 4; ++reg) {
          const int row = m0 + 32 * wq + 16 * mt + 4 * (lane >> 4) + reg;
          O[(size_t)row * 128 + 16 * nt + lrow] = __float2half(acc[mt][nt][reg]);
        }
  } else {
    float* O = reinterpret_cast<float*>(Cout);
#pragma unroll
    for (int mt = 0; mt < 2; ++mt)
#pragma unroll
      for (int nt = 0; nt < 8; ++nt)
#pragma unroll
        for (int reg = 0; reg < 4; ++reg) {
          const int row = m0 + 32 * wq + 16 * mt + 4 * (lane >> 4) + reg;
          O[(size_t)row * N + n0 + 16 * nt + lrow] = acc[mt][nt][reg];
        }
  }
}

// ---------- split-f16 MFMA dot + argmin: z = argmin_s ||k - c_s||^2 --------
__global__ __launch_bounds__(256, 2) void argmin3_k(
    const __half* __restrict__ kbh, const __half* __restrict__ kbl,
    const __half* __restrict__ cbh, const __half* __restrict__ cbl,
    const float* __restrict__ cb2v, int* __restrict__ zb) {
  __shared__ __half BsH[64 * 136];
  __shared__ __half BsL[64 * 136];
  const int tid = threadIdx.x;
  const int lane = tid & 63, wq = tid >> 6;
  const int lrow = lane & 15, lk8 = (lane >> 4) << 3;
  const int m0 = blockIdx.x * 128;
  const int h = blockIdx.y;
  const int srow = tid >> 2, spart = tid & 3;
  const size_t kbase = (size_t)h * (Bn * Tn);

  half8 ah[2][4], al[2][4];
#pragma unroll
  for (int mt = 0; mt < 2; ++mt)
#pragma unroll
    for (int ks = 0; ks < 4; ++ks) {
      const size_t off =
          (kbase + m0 + 32 * wq + 16 * mt + lrow) * 128 + lk8 + 32 * ks;
      ah[mt][ks] = ldh8(kbh + off);
      al[mt][ks] = ldh8(kbl + off);
    }

  float best[2][4];
  int bidx[2][4];
#pragma unroll
  for (int mt = 0; mt < 2; ++mt)
#pragma unroll
    for (int reg = 0; reg < 4; ++reg) {
      best[mt][reg] = 3.0e38f;
      bidx[mt][reg] = 0;
    }

  for (int s0 = 0; s0 < Sn; s0 += 64) {
    __syncthreads();
    {
      const size_t bo = ((size_t)h * Sn + s0 + srow) * 128 + spart * 32;
      sth8(&BsH[srow * 136 + spart * 32], ldh8(cbh + bo));
      sth8(&BsH[srow * 136 + spart * 32 + 8], ldh8(cbh + bo + 8));
      sth8(&BsH[srow * 136 + spart * 32 + 16], ldh8(cbh + bo + 16));
      sth8(&BsH[srow * 136 + spart * 32 + 24], ldh8(cbh + bo + 24));
      sth8(&BsL[srow * 136 + spart * 32], ldh8(cbl + bo));
      sth8(&BsL[srow * 136 + spart * 32 + 8], ldh8(cbl + bo + 8));
      sth8(&BsL[srow * 136 + spart * 32 + 16], ldh8(cbl + bo + 16));
      sth8(&BsL[srow * 136 + spart * 32 + 24], ldh8(cbl + bo + 24));
    }
    __syncthreads();
    f32x4 acc[2][4];
#pragma unroll
    for (int mt = 0; mt < 2; ++mt)
#pragma unroll
      for (int nt = 0; nt < 4; ++nt) acc[mt][nt] = (f32x4){0.f, 0.f, 0.f, 0.f};
#pragma unroll
    for (int ks = 0; ks < 4; ++ks)
#pragma unroll
      for (int nt = 0; nt < 4; ++nt) {
        const half8 bh = ldh8(&BsH[(16 * nt + lrow) * 136 + lk8 + 32 * ks]);
        const half8 bl = ldh8(&BsL[(16 * nt + lrow) * 136 + lk8 + 32 * ks]);
        acc[0][nt] = mfma16(ah[0][ks], bh, acc[0][nt]);
        acc[0][nt] = mfma16(ah[0][ks], bl, acc[0][nt]);
        acc[0][nt] = mfma16(al[0][ks], bh, acc[0][nt]);
        acc[1][nt] = mfma16(ah[1][ks], bh, acc[1][nt]);
        acc[1][nt] = mfma16(ah[1][ks], bl, acc[1][nt]);
        acc[1][nt] = mfma16(al[1][ks], bh, acc[1][nt]);
      }
#pragma unroll
    for (int mt = 0; mt < 2; ++mt)
#pragma unroll
      for (int nt = 0; nt < 4; ++nt) {
        const int s = s0 + 16 * nt + lrow;
        const float c2 = cb2v[h * Sn + s];
#pragma unroll
        for (int reg = 0; reg < 4; ++reg) {
          const float d2 = c2 - 2.0f * acc[mt][nt][reg];
          if (d2 < best[mt][reg]) {
            best[mt][reg] = d2;
            bidx[mt][reg] = s;
          }
        }
      }
  }
#pragma unroll
  for (int xb = 1; xb <= 8; xb <<= 1) {
#pragma unroll
    for (int mt = 0; mt < 2; ++mt)
#pragma unroll
      for (int reg = 0; reg < 4; ++reg) {
        const float ob = __shfl_xor(best[mt][reg], xb);
        const int oi = __shfl_xor(bidx[mt][reg], xb);
        if (ob < best[mt][reg] ||
            (ob == best[mt][reg] && oi < bidx[mt][reg])) {
          best[mt][reg] = ob;
          bidx[mt][reg] = oi;
        }
      }
  }
  if (lrow == 0) {
#pragma unroll
    for (int mt = 0; mt < 2; ++mt)
#pragma unroll
      for (int reg = 0; reg < 4; ++reg) {
        const int row = m0 + 32 * wq + 16 * mt + 4 * (lane >> 4) + reg;
        zb[kbase + row] = bidx[mt][reg];
      }
  }
}

// ------- scan2: cumulative cluster stats, 256 blocks x 1024 thr ------------
// block = (s-chunk of 64, b, h); 8 token-slices x 128 dims
__global__ __launch_bounds__(1024) void scan2_k(const int* __restrict__ zb,
                                                const __half* __restrict__ vb,
                                                __half* __restrict__ udl,
                                                float* __restrict__ biasv) {
  __shared__ float acc[64][128];
  __shared__ float cnt[64];
  const int tid = threadIdx.x;
  const int sc = blockIdx.x, b = blockIdx.y, h = blockIdx.z;
  const int s0 = sc * 64;
  for (int i = tid; i < 64 * 128; i += 1024) acc[i >> 7][i & 127] = 0.f;
  if (tid < 64) cnt[tid] = 0.f;
  __syncthreads();
  const size_t tokH = (size_t)h * (Bn * Tn) + (size_t)b * Tn;
  const int dd = tid & 127, slice = tid >> 7;  // 8 slices
  for (int r = 0; r < Rn; ++r) {
    // write udl[r] (= cum through r-2) and bias[r]
    for (int i = tid; i < 64 * 128; i += 1024) {
      const int srow = i >> 7, d = i & 127;
      const float c = cnt[srow];
      udl[((((size_t)h * Bn + b) * Rn + r) * Sn + s0 + srow) * Vn + d] =
          __float2half(acc[srow][d] / fmaxf(c, 1.f));
    }
    if (tid < 64) {
      const float c = cnt[tid];
      biasv[(((size_t)h * Bn + b) * Rn + r) * Sn + s0 + tid] =
          (c > 0.f) ? logf(c) : -NEGV;
    }
    __syncthreads();
    // add tokens of block r-1 (next state = cum through r-1)
    if (r >= 1 && r < 7) {
      const int tb = (r - 1) * Cn;
#pragma unroll 4
      for (int u = 0; u < 32; ++u) {
        const int tok = tb + u * 8 + slice;
        const int s = zb[tokH + tok];
        if (s >= s0 && s < s0 + 64) {
          const float v = __half2float(vb[(tokH + tok) * Vn + dd]);
          atomicAdd(&acc[s - s0][dd], v);
          if (dd == 0) atomicAdd(&cnt[s - s0], 1.0f);
        }
      }
    }
    __syncthreads();
  }
}

// ---------------- MFMA fused attention ----------------
__global__ __launch_bounds__(256, 2) void attn3_k(
    const __half* __restrict__ qbh, const __half* __restrict__ vbh,
    const __half* __restrict__ udl, const __half* __restrict__ cbh,
    const __half* __restrict__ xlrh, const float* __restrict__ biasv,
    const float* __restrict__ duv, const int* __restrict__ zb,
    const float* __restrict__ xlu, __half* __restrict__ aout) {
  __shared__ __half quS[64 * 136];
  __shared__ __half KXS[64 * 136];
  __shared__ __half VtS[128 * 72];
  __shared__ __half PBD[64 * 136];
  __shared__ float duvS[128];
  __shared__ float biasS[64];

  const int tid = threadIdx.x;
  const int lane = tid & 63, wq = tid >> 6;
  const int lrow = lane & 15, lk8 = (lane >> 4) << 3;
  const int qt = blockIdx.x;
  const int b = blockIdx.y >> 3, r = blockIdx.y & 7;
  const int h = blockIdx.z;
  const int c0 = qt * 64;
  const int tBlk = r * Cn + c0;
  const size_t tokH = (size_t)h * (Bn * Tn) + (size_t)b * Tn;
  const size_t sBase = (((size_t)h * Bn + b) * Rn + r) * Sn;
  const int srow = tid >> 2, spart = tid & 3;
  const int kp = tid >> 3, p8 = tid & 7;

  {
    const __half* src = qbh + (tokH + tBlk + srow) * Kn + spart * 32;
    const float* up = xlu + h * Kn + spart * 32;
    alignas(16) __half tmp[32];
#pragma unroll
    for (int e = 0; e < 32; ++e)
      tmp[e] = __float2half(__half2float(src[e]) + up[e]);
#pragma unroll
    for (int g2 = 0; g2 < 4; ++g2)
      sth8(&quS[srow * 136 + spart * 32 + g2 * 8],
           *reinterpret_cast<half8*>(&tmp[g2 * 8]));
  }

  float mR[4], lR[4];
  f32x4 Oacc[8];
#pragma unroll
  for (int i = 0; i < 4; ++i) {
    mR[i] = -NEGV;
    lR[i] = 0.f;
  }
#pragma unroll
  for (int nt = 0; nt < 8; ++nt) Oacc[nt] = (f32x4){0.f, 0.f, 0.f, 0.f};

  half8 a[4];
  bool aLoaded = false;

  for (int ch = 0; ch < 16; ++ch) {
    const bool isC = (ch < 8);
    const int s0 = ch * 64;
    const int w0 = (ch - 8) * 64;
    const int jbase = w0 + 192 - c0;
    __syncthreads();
    if (isC) {
      const __half* ks = cbh + ((size_t)h * Sn + s0 + srow) * Kn + spart * 32;
      sth8(&KXS[srow * 136 + spart * 32], ldh8(ks));
      sth8(&KXS[srow * 136 + spart * 32 + 8], ldh8(ks + 8));
      sth8(&KXS[srow * 136 + spart * 32 + 16], ldh8(ks + 16));
      sth8(&KXS[srow * 136 + spart * 32 + 24], ldh8(ks + 24));
      const __half* u0 = udl + (sBase + s0 + 2 * kp) * Vn + p8 * 16;
      const __half* u1 = u0 + Vn;
#pragma unroll
      for (int e = 0; e < 16; ++e) {
        const int d = p8 * 16 + e;
        const int gidx = ((2 * kp) >> 3) ^ ((d >> 4) & 7);
        *reinterpret_cast<__half2*>(
            &VtS[d * 72 + gidx * 8 + ((2 * kp) & 7)]) =
            __halves2half2(u0[e], u1[e]);
      }
      if (tid < 64) biasS[tid] = biasv[sBase + s0 + tid];
    } else {
      int tk = (r - 1) * Cn + w0 + srow;
      if (tk < 0) tk = 0;
      const int code = zb[tokH + tk];
      const __half* ks = cbh + ((size_t)h * Sn + code) * Kn + spart * 32;
      sth8(&KXS[srow * 136 + spart * 32], ldh8(ks));
      sth8(&KXS[srow * 136 + spart * 32 + 8], ldh8(ks + 8));
      sth8(&KXS[srow * 136 + spart * 32 + 16], ldh8(ks + 16));
      sth8(&KXS[srow * 136 + spart * 32 + 24], ldh8(ks + 24));
      const int tk0 = (r - 1) * Cn + w0 + 2 * kp;
      const int tka = tk0 < 0 ? 0 : tk0;
      const int tkb = tk0 + 1 < 0 ? 0 : tk0 + 1;
      const __half* v0 = vbh + (tokH + tka) * Kn + p8 * 16;
      const __half* v1 = vbh + (tokH + tkb) * Kn + p8 * 16;
#pragma unroll
      for (int e = 0; e < 16; ++e) {
        const int d = p8 * 16 + e;
        const int gidx = ((2 * kp) >> 3) ^ ((d >> 4) & 7);
        *reinterpret_cast<__half2*>(
            &VtS[d * 72 + gidx * 8 + ((2 * kp) & 7)]) =
            __halves2half2(v0[e], v1[e]);
      }
    }
    __syncthreads();
    if (!aLoaded) {
#pragma unroll
      for (int ks = 0; ks < 4; ++ks)
        a[ks] = ldh8(&quS[(16 * wq + lrow) * 136 + lk8 + 32 * ks]);
      aLoaded = true;
    }
    f32x4 acc[4];
#pragma unroll
    for (int nt = 0; nt < 4; ++nt) acc[nt] = (f32x4){0.f, 0.f, 0.f, 0.f};
#pragma unroll
    for (int ks = 0; ks < 4; ++ks)
#pragma unroll
      for (int nt = 0; nt < 4; ++nt)
        acc[nt] = mfma16(
            a[ks], ldh8(&KXS[(16 * nt + lrow) * 136 + lk8 + 32 * ks]),
            acc[nt]);

    float lg[4][4];
    if (isC) {
#pragma unroll
      for (int nt = 0; nt < 4; ++nt) {
        const float bv = biasS[lrow + 16 * nt];
#pragma unroll
        for (int reg = 0; reg < 4; ++reg)
          lg[nt][reg] = acc[nt][reg] * INV_TAU + bv;
      }
    } else {
#pragma unroll
      for (int hh = 0; hh < 2; ++hh) {
        __syncthreads();
        {
          int j = jbase + hh * 64 + srow;
          j = j < 0 ? 0 : (j > Wn - 1 ? Wn - 1 : j);
          const __half* xs = xlrh + ((size_t)h * Wn + j) * Kn + spart * 32;
          sth8(&KXS[srow * 136 + spart * 32], ldh8(xs));
          sth8(&KXS[srow * 136 + spart * 32 + 8], ldh8(xs + 8));
          sth8(&KXS[srow * 136 + spart * 32 + 16], ldh8(xs + 16));
          sth8(&KXS[srow * 136 + spart * 32 + 24], ldh8(xs + 24));
          if (hh == 0 && tid < 128) {
            int jx = jbase + tid;
            jx = jx < 0 ? 0 : (jx > Wn - 1 ? Wn - 1 : jx);
            duvS[tid] = duv[h * Wn + jx];
          }
        }
        __syncthreads();
        f32x4 bdh[4];
#pragma unroll
        for (int nt = 0; nt < 4; ++nt) bdh[nt] = (f32x4){0.f, 0.f, 0.f, 0.f};
#pragma unroll
        for (int ks = 0; ks < 4; ++ks)
#pragma unroll
          for (int nt = 0; nt < 4; ++nt)
            bdh[nt] = mfma16(
                a[ks], ldh8(&KXS[(16 * nt + lrow) * 136 + lk8 + 32 * ks]),
                bdh[nt]);
#pragma unroll
        for (int nt = 0; nt < 4; ++nt) {
          const int col = hh * 64 + 16 * nt + lrow;
          const float dv = duvS[col];
#pragma unroll
          for (int reg = 0; reg < 4; ++reg) {
            const int row64 = 16 * wq + 4 * (lane >> 4) + reg;
            PBD[row64 * 136 + col] = __float2half(bdh[nt][reg] + dv);
          }
        }
      }
      __syncthreads();
#pragma unroll
      for (int nt = 0; nt < 4; ++nt) {
        const int key = lrow + 16 * nt;
        const int w = w0 + key;
#pragma unroll
        for (int reg = 0; reg < 4; ++reg) {
          const int row64 = 16 * wq + 4 * (lane >> 4) + reg;
          const bool valid = (w <= c0 + row64 + Cn) && !(r == 0 && w < Cn);
          const float bdv = __half2float(PBD[row64 * 136 + key + 63 - row64]);
          lg[nt][reg] = valid ? (acc[nt][reg] + bdv) * INV_TAU : -NEGV;
        }
      }
      __syncthreads();
    }
    float p[4][4], scl[4];
#pragma unroll
    for (int reg = 0; reg < 4; ++reg) {
      float rm = fmaxf(fmaxf(lg[0][reg], lg[1][reg]),
                       fmaxf(lg[2][reg], lg[3][reg]));
      rm = fmaxf(rm, __shfl_xor(rm, 1));
      rm = fmaxf(rm, __shfl_xor(rm, 2));
      rm = fmaxf(rm, __shfl_xor(rm, 4));
      rm = fmaxf(rm, __shfl_xor(rm, 8));
      const float mn = fmaxf(mR[reg], rm);
      scl[reg] = __expf(mR[reg] - mn);
      float rs = 0.f;
#pragma unroll
      for (int nt = 0; nt < 4; ++nt) {
        p[nt][reg] = __expf(lg[nt][reg] - mn);
        rs += p[nt][reg];
      }
      rs += __shfl_xor(rs, 1);
      rs += __shfl_xor(rs, 2);
      rs += __shfl_xor(rs, 4);
      rs += __shfl_xor(rs, 8);
      lR[reg] = lR[reg] * scl[reg] + rs;
      mR[reg] = mn;
    }
#pragma unroll
    for (int nt = 0; nt < 8; ++nt)
#pragma unroll
      for (int reg = 0; reg < 4; ++reg) Oacc[nt][reg] *= scl[reg];
#pragma unroll
    for (int nt = 0; nt < 4; ++nt)
#pragma unroll
      for (int reg = 0; reg < 4; ++reg) {
        const int row64 = 16 * wq + 4 * (lane >> 4) + reg;
        PBD[row64 * 136 + lrow + 16 * nt] = __float2half(p[nt][reg]);
      }
    __syncthreads();
#pragma unroll
    for (int ks = 0; ks < 2; ++ks) {
      half8 pa = ldh8(&PBD[(16 * wq + lrow) * 136 + lk8 + 32 * ks]);
#pragma unroll
      for (int nt = 0; nt < 8; ++nt) {
        const int gidx = (((lk8 + 32 * ks) >> 3) ^ nt);
        half8 vb = ldh8(&VtS[(16 * nt + lrow) * 72 + gidx * 8]);
        Oacc[nt] = mfma16(pa, vb, Oacc[nt]);
      }
    }
  }
  float inv[4];
#pragma unroll
  for (int reg = 0; reg < 4; ++reg) inv[reg] = 1.0f / lR[reg];
#pragma unroll
  for (int nt = 0; nt < 8; ++nt)
#pragma unroll
    for (int reg = 0; reg < 4; ++reg) {
      const int row64 = 16 * wq + 4 * (lane >> 4) + reg;
      aout[((size_t)b * Tn + tBlk + row64) * (Hn * Vn) + h * Vn + 16 * nt +
           lrow] = __float2half(Oacc[nt][reg] * inv[reg]);
    }
}

// ---------------- launcher ----------------
extern "C" void kernel_launch(void* const* d_in, const int* in_sizes, int n_in,
                              void* d_out, int out_size, void* d_ws,
                              size_t ws_size, hipStream_t stream) {
  (void)in_sizes;
  (void)n_in;
  (void)out_size;
  const float* x = (const float*)d_in[0];
  const float* g_ln = (const float*)d_in[1];
  const float* Wq = (const float*)d_in[2];
  const float* Wk = (const float*)d_in[3];
  const float* Wv = (const float*)d_in[4];
  const float* cb = (const float*)d_in[5];
  const float* xl_r = (const float*)d_in[6];
  const float* xl_u = (const float*)d_in[7];
  const float* xl_v = (const float*)d_in[8];
  const float* Wo = (const float*)d_in[9];
  float* out = (float*)d_out;

  float* W = (float*)d_ws;
  size_t o = 0;
  __half* xth = (__half*)(W + o);         // aliased later by aout (exact fit)
  __half* aout = xth;
  o += (size_t)Bn * Tn * Dn / 2;          // 4,194,304
  __half* xtl = (__half*)(W + o);
  o += (size_t)Bn * Tn * Dn / 2;          // 4,194,304
  __half* kbh = (__half*)(W + o);         // k hi/lo; aliased later by udl
  __half* udlh = kbh;                     // udl spans kbh+kbl (33.5 MB)
  o += (size_t)Hn * Bn * Tn * Kn / 2;     // 4,194,304
  __half* kbl = (__half*)(W + o);
  o += (size_t)Hn * Bn * Tn * Kn / 2;     // 4,194,304
  __half* qbh = (__half*)(W + o);
  o += (size_t)Hn * Bn * Tn * Kn / 2;     // 2,097,152
  __half* vbh = (__half*)(W + o);
  o += (size_t)Hn * Bn * Tn * Vn / 2;     // 2,097,152
  __half* cbh = (__half*)(W + o);
  o += (size_t)Hn * Sn * Kn / 2;          // 131,072
  __half* cbl = (__half*)(W + o);
  o += (size_t)Hn * Sn * Kn / 2;          // 131,072
  __half* xlrh = (__half*)(W + o);
  o += (size_t)Hn * Wn * Kn / 2;          // 131,072
  int* zb = (int*)(W + o);
  o += (size_t)Hn * Bn * Tn;              // 65,536
  float* biasb = W + o;
  o += (size_t)Hn * Bn * Rn * Sn;         // 131,072
  float* duvb = W + o;
  o += (size_t)Hn * Wn;                   // 4,096
  float* cb2b = W + o;
  o += (size_t)Hn * Sn;                   // 4,096
  __half* wkth = (__half*)(W + o);
  o += (size_t)Dn * Dn / 2;               // 524,288
  __half* wktl = (__half*)(W + o);
  o += (size_t)Dn * Dn / 2;
  __half* wqt = (__half*)(W + o);
  o += (size_t)Dn * Dn / 2;
  __half* wvt = (__half*)(W + o);
  o += (size_t)Dn * Dn / 2;
  __half* wot = (__half*)(W + o);
  o += (size_t)Dn * Dn / 2;

  if (ws_size < o * sizeof(float)) return;  // bail visibly if ws too small

  rms3_k<<<Bn * Tn, 256, 0, stream>>>(x, g_ln, xth, xtl);
  transcvt2_k<<<dim3(32, 32), 256, 0, stream>>>(Wk, wkth, wktl);
  transcvt_k<<<dim3(32, 32), 256, 0, stream>>>(Wq, wqt);
  transcvt_k<<<dim3(32, 32), 256, 0, stream>>>(Wv, wvt);
  transcvt_k<<<dim3(32, 32), 256, 0, stream>>>(Wo, wot);
  cb2_k<<<Hn * Sn / 256, 256, 0, stream>>>(cb, cb2b);
  cvt2_k<<<2 * Hn * Sn * Kn / 256, 256, 0, stream>>>(cb, xl_r, cbh, cbl, xlrh);
  duv_k<<<Hn, 256, 0, stream>>>(xl_r, xl_u, xl_v, duvb);

  kproj_k<<<dim3(64, 8), 256, 0, stream>>>(xth, xtl, wkth, wktl, kbh, kbl,
                                           8192, 1024);
  gemmh_k<0><<<dim3(64, 8), 256, 0, stream>>>(xth, wqt, qbh, 8192, 1024, 1024);
  gemmh_k<0><<<dim3(64, 8), 256, 0, stream>>>(xth, wvt, vbh, 8192, 1024, 1024);

  argmin3_k<<<dim3(Bn * Tn / 128, Hn), 256, 0, stream>>>(kbh, kbl, cbh, cbl,
                                                         cb2b, zb);
  scan2_k<<<dim3(8, Bn, Hn), 1024, 0, stream>>>(zb, vbh, udlh, biasb);

  attn3_k<<<dim3(4, Bn * Rn, Hn), 256, 0, stream>>>(
      qbh, vbh, udlh, cbh, xlrh, biasb, duvb, zb, xl_u, aout);

  gemmh_k<1><<<dim3(64, 8), 256, 0, stream>>>(aout, wot, out, 8192, 1024,
                                              1024);
}